// Round 3
// baseline (529.084 us; speedup 1.0000x reference)
//
#include <hip/hip_runtime.h>
#include <hip/hip_bf16.h>
#include <math.h>

#define NA 10000
#define NE 256000
#define FDIM 128
#define F3 384
#define NRBF 20
#define NLAYERS 3
#define NMOLS 100
#define CAP 96
#define WROW 388  // padded w_lds row (bf16): conflict-free MFMA-C transpose (verified R6)
#define PACK_BLOCKS 2288  // 585728 / 256
#define CUTOFF_F 5.0f
#define EPS_F 1e-8f
#define PI_F 3.14159265358979323846f

typedef __attribute__((ext_vector_type(8))) short bf16x8;
typedef __attribute__((ext_vector_type(4))) float f32x4;

// 12-byte fused record: {phi0, phi1, phi2, v0, v1, v2} bf16
struct pv6 { unsigned int u0, u1, u2; };

__device__ __forceinline__ float silu_f(float x) { return x / (1.0f + __expf(-x)); }

__device__ __forceinline__ unsigned short f2bf(float x) {
  unsigned u = __float_as_uint(x);
  return (unsigned short)((u + 0x7FFFu + ((u >> 16) & 1u)) >> 16);
}
__device__ __forceinline__ float bf2f(unsigned short u) {
  return __uint_as_float(((unsigned)u) << 16);
}
__device__ __forceinline__ float lo_f(unsigned int u) { return bf2f((unsigned short)(u & 0xFFFFu)); }
__device__ __forceinline__ float hi_f(unsigned int u) { return bf2f((unsigned short)(u >> 16)); }

// ---------------- weight pack helpers -> B-fragment bf16 layout ----------------
__device__ __forceinline__ void pack_one(const float* __restrict__ src,
                                         unsigned short* __restrict__ dst,
                                         int loc, int per, int N) {
  int lay = loc / per;
  int kn = loc - lay * per;
  int k = kn / N, n = kn - k * N;
  int kb = k >> 5, q = (k >> 3) & 3, j = k & 7, nt = n >> 4, c = n & 15;
  int NT = N >> 4;
  dst[(size_t)lay * per + (((kb * NT + nt) * 64 + (q * 16 + c)) * 8 + j)] = f2bf(src[loc]);
}

// dist_W padded pack: K=32 (rows 0..19 = dW, row 20 = db, rest 0), N=384
__device__ __forceinline__ void pack_dw(const float* __restrict__ dW,
                                        const float* __restrict__ db,
                                        unsigned short* __restrict__ dst, int loc) {
  int lay = loc / 12288;
  int kn = loc - lay * 12288;
  int k = kn / 384, n = kn - k * 384;
  float val = 0.0f;
  if (k < NRBF) val = dW[lay * NRBF * 384 + k * 384 + n];
  else if (k == NRBF) val = db[lay * 384 + n];
  int q = (k >> 3) & 3, j = k & 7, nt = n >> 4, c = n & 15;
  dst[(size_t)lay * 12288 + ((nt * 64 + (q * 16 + c)) * 8 + j)] = f2bf(val);
}

// ---------------- merged prep: blocks [0,PACK_BLOCKS) = weight pack; rest = geometry ----------------
__global__ __launch_bounds__(256) void prep_kernel(
    const float* __restrict__ msgW1, const float* __restrict__ msgW2,
    const float* __restrict__ updU, const float* __restrict__ updV,
    const float* __restrict__ updW1, const float* __restrict__ updW2,
    const float* __restrict__ rW1, const float* __restrict__ distW,
    const float* __restrict__ distb, unsigned short* __restrict__ dst,
    const float* __restrict__ xyz, const int* __restrict__ nbrs,
    float* __restrict__ unitv, unsigned short* __restrict__ rbf_bf,
    float* __restrict__ fcut,
    int* __restrict__ deg, int* __restrict__ slot_e, int* __restrict__ slot_j) {
  int b = blockIdx.x;
  if (b < PACK_BLOCKS) {
    int t = b * 256 + threadIdx.x;
    if (t < 49152) pack_one(msgW1, dst, t, 16384, 128);
    else if (t < 196608) pack_one(msgW2, dst + 49152, t - 49152, 49152, 384);
    else if (t < 245760) pack_one(updU, dst + 196608, t - 196608, 16384, 128);
    else if (t < 294912) pack_one(updV, dst + 245760, t - 245760, 16384, 128);
    else if (t < 393216) pack_one(updW1, dst + 294912, t - 294912, 32768, 128);
    else if (t < 540672) pack_one(updW2, dst + 393216, t - 393216, 49152, 384);
    else if (t < 548864) pack_one(rW1, dst + 540672, t - 540672, 8192, 64);
    else if (t < 585728) pack_dw(distW, distb, dst + 548864, t - 548864);
    return;
  }
  int e = (b - PACK_BLOCKS) * 256 + threadIdx.x;
  if (e >= NE) return;
  int i = nbrs[2 * e + 0], j = nbrs[2 * e + 1];
  float rx = xyz[3 * j + 0] - xyz[3 * i + 0];
  float ry = xyz[3 * j + 1] - xyz[3 * i + 1];
  float rz = xyz[3 * j + 2] - xyz[3 * i + 2];
  float d = sqrtf(rx * rx + ry * ry + rz * rz + EPS_F);
  if (d >= CUTOFF_F) return;
  float invd = 1.0f / d;
  float fc = 0.5f * (__cosf(PI_F * d / CUTOFF_F) + 1.0f);
  unitv[3 * e + 0] = rx * invd;
  unitv[3 * e + 1] = ry * invd;
  unitv[3 * e + 2] = rz * invd;
  fcut[e] = fc;
  float base = PI_F * d / CUTOFF_F;
  float sc = invd * fc;
#pragma unroll
  for (int k = 0; k < NRBF; k++)
    rbf_bf[(size_t)e * NRBF + k] = f2bf(__sinf((float)(k + 1) * base) * sc);
  int pos = atomicAdd(&deg[i], 1);
  if (pos < CAP) {
    slot_e[i * CAP + pos] = e;
    slot_j[i * CAP + pos] = j;
  }
}

// ---------------- layer-0 message MLP (fused s = emb[z] init); writes pv6 {phi, v=0} ----------------
__global__ __launch_bounds__(256) void msg0_mfma_kernel(
    const float* __restrict__ emb, const int* __restrict__ z, float* __restrict__ s_out,
    const unsigned short* __restrict__ pW1, const float* __restrict__ b1,
    const unsigned short* __restrict__ pW2, const float* __restrict__ b2,
    pv6* __restrict__ cmb) {
  __shared__ bf16x8 sA[4 * 64];
  __shared__ bf16x8 hA[4 * 64];
  int a0 = blockIdx.x * 16;
  int t = threadIdx.x;
  int lane = t & 63, w = t >> 6;
  {
    int kb = t >> 6, l = t & 63;
    int m = l & 15, q = l >> 4;
    int zi = z[a0 + m];
    const float* sp = emb + (size_t)zi * FDIM + kb * 32 + q * 8;
    float* so = s_out + (size_t)(a0 + m) * FDIM + kb * 32 + q * 8;
    bf16x8 c;
#pragma unroll
    for (int j = 0; j < 8; j++) {
      float v = sp[j];
      so[j] = v;
      c[j] = (short)f2bf(v);
    }
    sA[kb * 64 + l] = c;
  }
  __syncthreads();
  f32x4 accH[2];
#pragma unroll
  for (int t2 = 0; t2 < 2; t2++)
#pragma unroll
    for (int r = 0; r < 4; r++) accH[t2][r] = 0.0f;
  const bf16x8* W1f = (const bf16x8*)pW1;
#pragma unroll
  for (int kb = 0; kb < 4; kb++) {
    bf16x8 a = sA[kb * 64 + lane];
#pragma unroll
    for (int t2 = 0; t2 < 2; t2++) {
      bf16x8 b = W1f[(kb * 8 + 2 * w + t2) * 64 + lane];
      accH[t2] = __builtin_amdgcn_mfma_f32_16x16x32_bf16(a, b, accH[t2], 0, 0, 0);
    }
  }
  short* hs = (short*)hA;
#pragma unroll
  for (int t2 = 0; t2 < 2; t2++) {
    int n = w * 32 + t2 * 16 + (lane & 15);
    int kb = n >> 5, q = (n >> 3) & 3, j = n & 7;
    float bias = b1[n];
#pragma unroll
    for (int r = 0; r < 4; r++) {
      int m = (lane >> 4) * 4 + r;
      hs[(kb * 64 + q * 16 + m) * 8 + j] = (short)f2bf(silu_f(accH[t2][r] + bias));
    }
  }
  __syncthreads();
  f32x4 accP[3][2];
#pragma unroll
  for (int c3 = 0; c3 < 3; c3++)
#pragma unroll
    for (int t2 = 0; t2 < 2; t2++)
#pragma unroll
      for (int r = 0; r < 4; r++) accP[c3][t2][r] = 0.0f;
  const bf16x8* W2f = (const bf16x8*)pW2;
#pragma unroll
  for (int kb = 0; kb < 4; kb++) {
    bf16x8 a = hA[kb * 64 + lane];
#pragma unroll
    for (int c3 = 0; c3 < 3; c3++)
#pragma unroll
      for (int t2 = 0; t2 < 2; t2++) {
        bf16x8 b = W2f[(kb * 24 + c3 * 8 + 2 * w + t2) * 64 + lane];
        accP[c3][t2] = __builtin_amdgcn_mfma_f32_16x16x32_bf16(a, b, accP[c3][t2], 0, 0, 0);
      }
  }
#pragma unroll
  for (int t2 = 0; t2 < 2; t2++) {
    int g = (2 * w + t2) * 16 + (lane & 15);
    float bb0 = b2[g], bb1 = b2[FDIM + g], bb2 = b2[2 * FDIM + g];
#pragma unroll
    for (int r = 0; r < 4; r++) {
      int m = (lane >> 4) * 4 + r;
      unsigned p0 = f2bf(accP[0][t2][r] + bb0);
      unsigned p1 = f2bf(accP[1][t2][r] + bb1);
      unsigned p2 = f2bf(accP[2][t2][r] + bb2);
      pv6 rec;
      rec.u0 = p0 | (p1 << 16);
      rec.u1 = p2;
      rec.u2 = 0;
      cmb[(size_t)(a0 + m) * FDIM + g] = rec;
    }
  }
}

// ---------------- edge aggregation helpers ----------------
// A-fragment prefetch: lane's 8 rbf slots (+fcut at k==20) for edge c0+(lane&15).
__device__ __forceinline__ void afrag_load(const unsigned short* __restrict__ rbf_bf,
                                           const float* __restrict__ fcut,
                                           const int* l_e_all, int cnt, int c0,
                                           int m16, int q4,
                                           unsigned short apf[8], float* afc) {
#pragma unroll
  for (int j = 0; j < 8; j++) apf[j] = 0;
  *afc = 0.0f;
  int p = c0 + m16;
  if (p < cnt && q4 < 3) {
    int e = l_e_all[p];
    const unsigned short* rb = rbf_bf + (size_t)e * NRBF;
    if (q4 < 2) {
#pragma unroll
      for (int j = 0; j < 8; j++) apf[j] = rb[q4 * 8 + j];
    } else {
#pragma unroll
      for (int j = 0; j < 4; j++) apf[j] = rb[16 + j];
      *afc = fcut[e];
    }
  }
}

__device__ __forceinline__ void proc1(const pv6& R, float wv0, float wv1, float wv2,
                                      const float* lu,
                                      float& as, float& v0, float& v1, float& v2) {
  float p0 = lo_f(R.u0), p1 = hi_f(R.u0), p2 = lo_f(R.u1);
  float x0 = hi_f(R.u1), x1 = lo_f(R.u2), x2 = hi_f(R.u2);
  as += p0 * wv0;
  float i1 = p1 * wv1, i2 = p2 * wv2;
  v0 += i1 * x0 + i2 * lu[0];
  v1 += i1 * x1 + i2 * lu[1];
  v2 += i1 * x2 + i2 * lu[2];
}

// unguarded 4-edge gather (both features) — only called for full batches
#define LOAD4(X0, X1, P)                                   \
  {                                                        \
    _Pragma("unroll") for (int u = 0; u < 4; u++) {        \
      size_t row = (size_t)l_j_all[(P) + u] * FDIM;        \
      X0[u] = cmb[row + f0];                               \
      X1[u] = cmb[row + f1];                               \
    }                                                      \
  }

#define PROC4(X0, X1, PP)                                                                  \
  {                                                                                        \
    _Pragma("unroll") for (int u = 0; u < 4; u++) {                                        \
      const unsigned short* wr = w_lds[w][(PP) + u];                                       \
      const float* lu = l_u[w][(PP) + u];                                                  \
      proc1(X0[u], bf2f(wr[f0]), bf2f(wr[FDIM + f0]), bf2f(wr[2 * FDIM + f0]), lu,         \
            s0, a00, a01, a02);                                                            \
      proc1(X1[u], bf2f(wr[f1]), bf2f(wr[FDIM + f1]), bf2f(wr[2 * FDIM + f1]), lu,         \
            s1, a10, a11, a12);                                                            \
    }                                                                                      \
  }

// ---------------- edge aggregation: 2 independent waves, wave-private chunks, no intra-loop barriers ----------------
// Wave w owns 16-edge chunks at c0 = 16*w, 16*w+32, ... and computes the FULL
// 16x384 w_s tile itself (24 MFMA); lane holds features f0=lane, f1=lane+64.
// Only same-wave lgkmcnt ordering needed between ds_write and ds_read.
// Cross-wave partial reduction once at the end (2 barriers total).
__global__ __launch_bounds__(128) void edge_kernel(
    const pv6* __restrict__ cmb, unsigned short* __restrict__ v_lin,
    float* __restrict__ s, const unsigned short* __restrict__ pDW,
    const int* __restrict__ deg, const int* __restrict__ slot_e,
    const int* __restrict__ slot_j, const unsigned short* __restrict__ rbf_bf,
    const float* __restrict__ fcut, const float* __restrict__ unitv) {
  __shared__ __align__(16) unsigned short w_lds[2][16][WROW];
  __shared__ float l_u[2][16][3];
  __shared__ int l_e_all[CAP];
  __shared__ int l_j_all[CAP];
  int i = blockIdx.x;
  int t = threadIdx.x;
  int lane = t & 63, w = t >> 6;
  int f0 = lane, f1 = lane + 64;
  int cnt = deg[i];
  if (cnt > CAP) cnt = CAP;
  int base = i * CAP;
  if (t < cnt) {
    l_e_all[t] = slot_e[base + t];
    l_j_all[t] = slot_j[base + t];
  }
  __syncthreads();
  float s0 = 0.f, s1 = 0.f;
  float a00 = 0.f, a01 = 0.f, a02 = 0.f;
  float a10 = 0.f, a11 = 0.f, a12 = 0.f;
  const bf16x8* Bf = (const bf16x8*)pDW;
  int m16 = lane & 15, q4 = lane >> 4;
  unsigned short apf[8];
  float afc = 0.0f;
  {
    int c00 = 16 * w;
    if (c00 < cnt) afrag_load(rbf_bf, fcut, l_e_all, cnt, c00, m16, q4, apf, &afc);
  }
  for (int c0 = 16 * w; c0 < cnt; c0 += 32) {
    int ccnt = cnt - c0;
    if (ccnt > 16) ccnt = 16;
    // wave-private l_u fill (lanes 0..15 of this wave)
    if (lane < 16) {
      int p = c0 + lane;
      if (p < cnt) {
        int e = l_e_all[p];
        l_u[w][lane][0] = unitv[3 * e + 0];
        l_u[w][lane][1] = unitv[3 * e + 1];
        l_u[w][lane][2] = unitv[3 * e + 2];
      }
    }
    // A fragment from prefetched registers
    bf16x8 a;
#pragma unroll
    for (int j = 0; j < 8; j++) a[j] = (short)apf[j];
    if (q4 == 2) a[4] = (short)f2bf(afc);
    // full w_s tile for this chunk: 24 MFMA by this wave alone
#pragma unroll
    for (int tt = 0; tt < 24; tt++) {
      f32x4 acc;
#pragma unroll
      for (int r = 0; r < 4; r++) acc[r] = 0.0f;
      acc = __builtin_amdgcn_mfma_f32_16x16x32_bf16(a, Bf[tt * 64 + lane], acc, 0, 0, 0);
      int n = tt * 16 + m16;
#pragma unroll
      for (int r = 0; r < 4; r++) w_lds[w][q4 * 4 + r][n] = f2bf(acc[r]);
    }
    // prefetch next chunk's A-frag (lands during gather phase)
    if (c0 + 32 < cnt) afrag_load(rbf_bf, fcut, l_e_all, cnt, c0 + 32, m16, q4, apf, &afc);
    int nb = ccnt >> 2;  // uniform per wave -> scalar branches
    pv6 A0[4], A1[4], B0[4], B1[4];
    if (nb > 0) LOAD4(A0, A1, c0 + 0);
    if (nb > 1) LOAD4(B0, B1, c0 + 4);
    // own ds_writes (w_lds + l_u) drained; gather loads above stay in flight
    asm volatile("s_waitcnt lgkmcnt(0)" ::: "memory");
    if (nb > 0) PROC4(A0, A1, 0);
    if (nb > 2) LOAD4(A0, A1, c0 + 8);
    if (nb > 1) PROC4(B0, B1, 4);
    if (nb > 3) LOAD4(B0, B1, c0 + 12);
    if (nb > 2) PROC4(A0, A1, 8);
    if (nb > 3) PROC4(B0, B1, 12);
    for (int pp = nb * 4; pp < ccnt; pp++) {
      size_t row = (size_t)l_j_all[c0 + pp] * FDIM;
      pv6 Rx = cmb[row + f0], Ry = cmb[row + f1];
      const unsigned short* wr = w_lds[w][pp];
      const float* lu = l_u[w][pp];
      proc1(Rx, bf2f(wr[f0]), bf2f(wr[FDIM + f0]), bf2f(wr[2 * FDIM + f0]), lu,
            s0, a00, a01, a02);
      proc1(Ry, bf2f(wr[f1]), bf2f(wr[FDIM + f1]), bf2f(wr[2 * FDIM + f1]), lu,
            s1, a10, a11, a12);
    }
  }
  // cross-wave partial reduction via LDS (aliases w_lds; all loop use finished)
  __syncthreads();
  f32x4* part = (f32x4*)w_lds;
  {
    f32x4 p0v, p1v;
    p0v[0] = s0; p0v[1] = a00; p0v[2] = a01; p0v[3] = a02;
    p1v[0] = s1; p1v[1] = a10; p1v[2] = a11; p1v[3] = a12;
    part[w * 128 + f0] = p0v;
    part[w * 128 + f1] = p1v;
  }
  __syncthreads();
  {
    f32x4 q0 = part[t], q1 = part[128 + t];
    float accs = q0[0] + q1[0];
    float v0 = q0[1] + q1[1];
    float v1 = q0[2] + q1[2];
    float v2 = q0[3] + q1[3];
    // own-atom v add: cmb v-halves are 0 for layer 0, so unconditional is correct
    pv6 RI = cmb[(size_t)i * FDIM + t];
    v0 += hi_f(RI.u1);
    v1 += lo_f(RI.u2);
    v2 += hi_f(RI.u2);
    unsigned short* vlo = v_lin + (size_t)i * F3;
    vlo[t] = f2bf(v0);
    vlo[FDIM + t] = f2bf(v1);
    vlo[2 * FDIM + t] = f2bf(v2);
    s[(size_t)i * FDIM + t] += accs;
  }
}

// ---------------- fused update (+ next-layer msg, or atom-energy readout) ----------------
// v_old re-read from vAf LDS (still live); u2 stored in s-epilogue; v0 kept in regs for msg epilogue.
__global__ __launch_bounds__(256) void upd_fused_kernel(
    float* __restrict__ s, const unsigned short* __restrict__ v_lin,
    pv6* __restrict__ cmb,
    const unsigned short* __restrict__ pU, const unsigned short* __restrict__ pV,
    const unsigned short* __restrict__ pW1, const float* __restrict__ b1,
    const unsigned short* __restrict__ pW2, const float* __restrict__ b2,
    int mode,
    const unsigned short* __restrict__ pMW1, const float* __restrict__ mb1,
    const unsigned short* __restrict__ pMW2, const float* __restrict__ mb2,
    const unsigned short* __restrict__ pRW1, const float* __restrict__ rb1,
    const float* __restrict__ rW2, const float* __restrict__ rb2,
    float* __restrict__ atom_e) {
  __shared__ bf16x8 vAf[3 * 4 * 64];
  __shared__ bf16x8 catA[8 * 64];
  __shared__ bf16x8 hA[4 * 64];
  __shared__ float red[4][16];
  int a0 = blockIdx.x * 16;
  int t = threadIdx.x;
  int lane = t & 63, w = t >> 6;
  {
    int l = t & 63, kb = (t >> 6) & 3;
    int m = l & 15, q = l >> 4;
#pragma unroll
    for (int rt = 0; rt < 3; rt++) {
      vAf[(rt * 4 + kb) * 64 + l] =
          *(const bf16x8*)(v_lin + (size_t)(a0 + m) * F3 + rt * FDIM + kb * 32 + q * 8);
    }
    const float* sp = s + (size_t)(a0 + m) * FDIM + kb * 32 + q * 8;
    bf16x8 c;
#pragma unroll
    for (int j = 0; j < 8; j++) c[j] = (short)f2bf(sp[j]);
    catA[kb * 64 + l] = c;
  }
  __syncthreads();
  f32x4 accU[3][2], accV[3][2];
#pragma unroll
  for (int rt = 0; rt < 3; rt++)
#pragma unroll
    for (int t2 = 0; t2 < 2; t2++)
#pragma unroll
      for (int r = 0; r < 4; r++) { accU[rt][t2][r] = 0.0f; accV[rt][t2][r] = 0.0f; }
  const bf16x8* Uf = (const bf16x8*)pU;
  const bf16x8* Vf = (const bf16x8*)pV;
#pragma unroll
  for (int kb = 0; kb < 4; kb++) {
    bf16x8 bu[2], bv[2];
#pragma unroll
    for (int t2 = 0; t2 < 2; t2++) {
      bu[t2] = Uf[(kb * 8 + 2 * w + t2) * 64 + lane];
      bv[t2] = Vf[(kb * 8 + 2 * w + t2) * 64 + lane];
    }
#pragma unroll
    for (int rt = 0; rt < 3; rt++) {
      bf16x8 a = vAf[(rt * 4 + kb) * 64 + lane];
#pragma unroll
      for (int t2 = 0; t2 < 2; t2++) {
        accU[rt][t2] = __builtin_amdgcn_mfma_f32_16x16x32_bf16(a, bu[t2], accU[rt][t2], 0, 0, 0);
        accV[rt][t2] = __builtin_amdgcn_mfma_f32_16x16x32_bf16(a, bv[t2], accV[rt][t2], 0, 0, 0);
      }
    }
  }
  short* cs = (short*)catA;
#pragma unroll
  for (int t2 = 0; t2 < 2; t2++) {
    int g = w * 32 + t2 * 16 + (lane & 15);
    int k = 128 + g;
    int kb = k >> 5, q = (k >> 3) & 3, j = k & 7;
#pragma unroll
    for (int r = 0; r < 4; r++) {
      int m = (lane >> 4) * 4 + r;
      float x0 = accV[0][t2][r], x1 = accV[1][t2][r], x2 = accV[2][t2][r];
      cs[(kb * 64 + q * 16 + m) * 8 + j] = (short)f2bf(sqrtf(x0 * x0 + x1 * x1 + x2 * x2 + EPS_F));
    }
  }
  __syncthreads();
  f32x4 accH[2];
#pragma unroll
  for (int t2 = 0; t2 < 2; t2++)
#pragma unroll
    for (int r = 0; r < 4; r++) accH[t2][r] = 0.0f;
  const bf16x8* W1f = (const bf16x8*)pW1;
#pragma unroll
  for (int kb = 0; kb < 8; kb++) {
    bf16x8 a = catA[kb * 64 + lane];
#pragma unroll
    for (int t2 = 0; t2 < 2; t2++) {
      bf16x8 b = W1f[(kb * 8 + 2 * w + t2) * 64 + lane];
      accH[t2] = __builtin_amdgcn_mfma_f32_16x16x32_bf16(a, b, accH[t2], 0, 0, 0);
    }
  }
  short* hs = (short*)hA;
#pragma unroll
  for (int t2 = 0; t2 < 2; t2++) {
    int n = w * 32 + t2 * 16 + (lane & 15);
    int kb = n >> 5, q = (n >> 3) & 3, j = n & 7;
    float bias = b1[n];
#pragma unroll
    for (int r = 0; r < 4; r++) {
      int m = (lane >> 4) * 4 + r;
      hs[(kb * 64 + q * 16 + m) * 8 + j] = (short)f2bf(silu_f(accH[t2][r] + bias));
    }
  }
  __syncthreads();
  f32x4 accA[3][2];
#pragma unroll
  for (int c3 = 0; c3 < 3; c3++)
#pragma unroll
    for (int t2 = 0; t2 < 2; t2++)
#pragma unroll
      for (int r = 0; r < 4; r++) accA[c3][t2][r] = 0.0f;
  const bf16x8* W2f = (const bf16x8*)pW2;
#pragma unroll
  for (int kb = 0; kb < 4; kb++) {
    bf16x8 a = hA[kb * 64 + lane];
#pragma unroll
    for (int c3 = 0; c3 < 3; c3++)
#pragma unroll
      for (int t2 = 0; t2 < 2; t2++) {
        bf16x8 b = W2f[(kb * 24 + c3 * 8 + 2 * w + t2) * 64 + lane];
        accA[c3][t2] = __builtin_amdgcn_mfma_f32_16x16x32_bf16(a, b, accA[c3][t2], 0, 0, 0);
      }
  }
  const short* vls = (const short*)vAf;  // v_old still live in LDS A-frag layout
  unsigned short v0keep[2][4];
#pragma unroll
  for (int t2 = 0; t2 < 2; t2++) {
    int g = w * 32 + t2 * 16 + (lane & 15);
    float bb0 = b2[g], bb1 = b2[FDIM + g], bb2 = b2[2 * FDIM + g];
    int kb = g >> 5, q = (g >> 3) & 3, j = g & 7;
#pragma unroll
    for (int r = 0; r < 4; r++) {
      int m = (lane >> 4) * 4 + r;
      int n = a0 + m;
      float a0v = accA[0][t2][r] + bb0;
      float a1v = accA[1][t2][r] + bb1;
      float a2v = accA[2][t2][r] + bb2;
      float dot = accU[0][t2][r] * accV[0][t2][r] + accU[1][t2][r] * accV[1][t2][r] +
                  accU[2][t2][r] * accV[2][t2][r];
      float s_new = s[(size_t)n * FDIM + g] + a1v * dot + a2v;
      if (mode == 0) {
        s[(size_t)n * FDIM + g] = s_new;
        float nv[3];
#pragma unroll
        for (int c = 0; c < 3; c++) {
          float vold = bf2f((unsigned short)vls[(((c * 4 + kb) * 64) + (q * 16 + m)) * 8 + j]);
          nv[c] = vold + a0v * accU[c][t2][r];
        }
        v0keep[t2][r] = f2bf(nv[0]);
        cmb[(size_t)n * FDIM + g].u2 = (unsigned)f2bf(nv[1]) | ((unsigned)f2bf(nv[2]) << 16);
      }
      cs[(kb * 64 + q * 16 + m) * 8 + j] = (short)f2bf(s_new);
    }
  }
  __syncthreads();
  if (mode == 0) {
    f32x4 accH2[2];
#pragma unroll
    for (int t2 = 0; t2 < 2; t2++)
#pragma unroll
      for (int r = 0; r < 4; r++) accH2[t2][r] = 0.0f;
    const bf16x8* MW1f = (const bf16x8*)pMW1;
#pragma unroll
    for (int kb = 0; kb < 4; kb++) {
      bf16x8 a = catA[kb * 64 + lane];
#pragma unroll
      for (int t2 = 0; t2 < 2; t2++) {
        bf16x8 b = MW1f[(kb * 8 + 2 * w + t2) * 64 + lane];
        accH2[t2] = __builtin_amdgcn_mfma_f32_16x16x32_bf16(a, b, accH2[t2], 0, 0, 0);
      }
    }
#pragma unroll
    for (int t2 = 0; t2 < 2; t2++) {
      int n = w * 32 + t2 * 16 + (lane & 15);
      int kb = n >> 5, q = (n >> 3) & 3, j = n & 7;
      float bias = mb1[n];
#pragma unroll
      for (int r = 0; r < 4; r++) {
        int m = (lane >> 4) * 4 + r;
        hs[(kb * 64 + q * 16 + m) * 8 + j] = (short)f2bf(silu_f(accH2[t2][r] + bias));
      }
    }
    __syncthreads();
    f32x4 accP[3][2];
#pragma unroll
    for (int c3 = 0; c3 < 3; c3++)
#pragma unroll
      for (int t2 = 0; t2 < 2; t2++)
#pragma unroll
        for (int r = 0; r < 4; r++) accP[c3][t2][r] = 0.0f;
    const bf16x8* MW2f = (const bf16x8*)pMW2;
#pragma unroll
    for (int kb = 0; kb < 4; kb++) {
      bf16x8 a = hA[kb * 64 + lane];
#pragma unroll
      for (int c3 = 0; c3 < 3; c3++)
#pragma unroll
        for (int t2 = 0; t2 < 2; t2++) {
          bf16x8 b = MW2f[(kb * 24 + c3 * 8 + 2 * w + t2) * 64 + lane];
          accP[c3][t2] = __builtin_amdgcn_mfma_f32_16x16x32_bf16(a, b, accP[c3][t2], 0, 0, 0);
        }
    }
#pragma unroll
    for (int t2 = 0; t2 < 2; t2++) {
      int g = (2 * w + t2) * 16 + (lane & 15);
      float bb0 = mb2[g], bb1 = mb2[FDIM + g], bb2v = mb2[2 * FDIM + g];
#pragma unroll
      for (int r = 0; r < 4; r++) {
        int m = (lane >> 4) * 4 + r;
        unsigned p0 = f2bf(accP[0][t2][r] + bb0);
        unsigned p1 = f2bf(accP[1][t2][r] + bb1);
        unsigned p2 = f2bf(accP[2][t2][r] + bb2v);
        pv6* rec = &cmb[(size_t)(a0 + m) * FDIM + g];
        rec->u0 = p0 | (p1 << 16);
        rec->u1 = p2 | ((unsigned)v0keep[t2][r] << 16);
      }
    }
  } else {
    f32x4 acc;
#pragma unroll
    for (int r = 0; r < 4; r++) acc[r] = 0.0f;
    const bf16x8* RW1f = (const bf16x8*)pRW1;
#pragma unroll
    for (int kb = 0; kb < 4; kb++) {
      bf16x8 a = catA[kb * 64 + lane];
      bf16x8 b = RW1f[(kb * 4 + w) * 64 + lane];
      acc = __builtin_amdgcn_mfma_f32_16x16x32_bf16(a, b, acc, 0, 0, 0);
    }
    int col = w * 16 + (lane & 15);
    float bias = rb1[col], w2v = rW2[col];
    float val[4];
#pragma unroll
    for (int r = 0; r < 4; r++) val[r] = silu_f(acc[r] + bias) * w2v;
#pragma unroll
    for (int off = 1; off < 16; off <<= 1)
#pragma unroll
      for (int r = 0; r < 4; r++) val[r] += __shfl_xor(val[r], off, 64);
    if ((lane & 15) == 0) {
#pragma unroll
      for (int r = 0; r < 4; r++) red[w][(lane >> 4) * 4 + r] = val[r];
    }
    __syncthreads();
    if (t < 16) {
      atom_e[a0 + t] = red[0][t] + red[1][t] + red[2][t] + red[3][t] + rb2[0];
    }
  }
}

// ---------------- molecule segment-sum: LDS partials, ~3 global atomics per block ----------------
__global__ __launch_bounds__(256) void mol_reduce_kernel(
    const float* __restrict__ atom_e, const int* __restrict__ mol_idx,
    float* __restrict__ out) {
  __shared__ float molsum[NMOLS];
  int t = threadIdx.x;
  if (t < NMOLS) molsum[t] = 0.0f;
  __syncthreads();
  int n = blockIdx.x * 256 + t;
  if (n < NA) atomicAdd(&molsum[mol_idx[n]], atom_e[n]);
  __syncthreads();
  if (t < NMOLS && molsum[t] != 0.0f) atomicAdd(&out[t], molsum[t]);
}

extern "C" void kernel_launch(void* const* d_in, const int* in_sizes, int n_in,
                              void* d_out, int out_size, void* d_ws, size_t ws_size,
                              hipStream_t stream) {
  const float* xyz = (const float*)d_in[0];
  const int* z = (const int*)d_in[1];
  const int* nbrs = (const int*)d_in[2];
  const int* mol = (const int*)d_in[3];
  const float* emb = (const float*)d_in[4];
  const float* msgW1 = (const float*)d_in[5];
  const float* msgb1 = (const float*)d_in[6];
  const float* msgW2 = (const float*)d_in[7];
  const float* msgb2 = (const float*)d_in[8];
  const float* distW = (const float*)d_in[9];
  const float* distb = (const float*)d_in[10];
  const float* updU = (const float*)d_in[11];
  const float* updV = (const float*)d_in[12];
  const float* updW1 = (const float*)d_in[13];
  const float* updb1 = (const float*)d_in[14];
  const float* updW2 = (const float*)d_in[15];
  const float* updb2 = (const float*)d_in[16];
  const float* rW1 = (const float*)d_in[17];
  const float* rb1 = (const float*)d_in[18];
  const float* rW2 = (const float*)d_in[19];
  const float* rb2 = (const float*)d_in[20];

  float* ws = (float*)d_ws;
  float* s = ws;      ws += (size_t)NA * FDIM;
  float* fcut = ws;   ws += (size_t)NE;
  float* unitv = ws;  ws += (size_t)NE * 3;
  float* atom_e = ws; ws += (size_t)NA;
  int* deg = (int*)ws;
  int* slot_e = deg + NA;
  int* slot_j = slot_e + NA * CAP;
  unsigned short* pk = (unsigned short*)(((uintptr_t)(slot_j + NA * CAP) + 15) & ~(uintptr_t)15);
  unsigned short* pMsgW1 = pk;                       // 49152
  unsigned short* pMsgW2 = pMsgW1 + 49152;           // 147456
  unsigned short* pUpdU  = pMsgW2 + 147456;          // 49152
  unsigned short* pUpdV  = pUpdU + 49152;            // 49152
  unsigned short* pUpdW1 = pUpdV + 49152;            // 98304
  unsigned short* pUpdW2 = pUpdW1 + 98304;           // 147456
  unsigned short* pRW1   = pUpdW2 + 147456;          // 8192
  unsigned short* pDW    = pRW1 + 8192;              // 3*12288
  unsigned short* rbf_bf = (unsigned short*)(((uintptr_t)(pDW + 36864) + 15) & ~(uintptr_t)15);
  unsigned short* after_rbf = rbf_bf + (size_t)NE * NRBF + 8;
  pv6* cmb = (pv6*)(((uintptr_t)after_rbf + 15) & ~(uintptr_t)15);           // NA*128 x 12B
  unsigned short* v_lin = (unsigned short*)(cmb + (size_t)NA * FDIM);        // NA*384

  hipMemsetAsync(deg, 0, NA * sizeof(int), stream);
  hipMemsetAsync(d_out, 0, NMOLS * sizeof(float), stream);

  prep_kernel<<<PACK_BLOCKS + NE / 256, 256, 0, stream>>>(
      msgW1, msgW2, updU, updV, updW1, updW2, rW1, distW, distb, pMsgW1,
      xyz, nbrs, unitv, rbf_bf, fcut, deg, slot_e, slot_j);
  msg0_mfma_kernel<<<NA / 16, 256, 0, stream>>>(emb, z, s, pMsgW1, msgb1, pMsgW2, msgb2, cmb);

  for (int l = 0; l < NLAYERS; l++) {
    edge_kernel<<<NA, 128, 0, stream>>>(cmb, v_lin, s,
                                        pDW + (size_t)l * 12288,
                                        deg, slot_e, slot_j, rbf_bf, fcut, unitv);
    int mode = (l == NLAYERS - 1) ? 1 : 0;
    int lnext = (l + 1 < NLAYERS) ? l + 1 : 0;
    upd_fused_kernel<<<NA / 16, 256, 0, stream>>>(
        s, v_lin, cmb, pUpdU + (size_t)l * 16384, pUpdV + (size_t)l * 16384,
        pUpdW1 + (size_t)l * 32768, updb1 + (size_t)l * FDIM,
        pUpdW2 + (size_t)l * 49152, updb2 + (size_t)l * F3,
        mode,
        pMsgW1 + (size_t)lnext * 16384, msgb1 + (size_t)lnext * FDIM,
        pMsgW2 + (size_t)lnext * 49152, msgb2 + (size_t)lnext * F3,
        pRW1, rb1, rW2, rb2, atom_e);
  }
  mol_reduce_kernel<<<(NA + 255) / 256, 256, 0, stream>>>(atom_e, mol, (float*)d_out);
}

// Round 4
// 490.613 us; speedup vs baseline: 1.0784x; 1.0784x over previous
//
#include <hip/hip_runtime.h>
#include <hip/hip_bf16.h>
#include <math.h>

#define NA 10000
#define NE 256000
#define FDIM 128
#define F3 384
#define NRBF 20
#define NLAYERS 3
#define NMOLS 100
#define CAP 96
#define PACK_BLOCKS 2288  // 585728 / 256
#define CUTOFF_F 5.0f
#define EPS_F 1e-8f
#define PI_F 3.14159265358979323846f

typedef __attribute__((ext_vector_type(8))) short bf16x8;
typedef __attribute__((ext_vector_type(4))) float f32x4;

// 12-byte fused record: {phi0, phi1, phi2, v0, v1, v2} bf16
struct pv6 { unsigned int u0, u1, u2; };

__device__ __forceinline__ float silu_f(float x) { return x / (1.0f + __expf(-x)); }

__device__ __forceinline__ unsigned short f2bf(float x) {
  unsigned u = __float_as_uint(x);
  return (unsigned short)((u + 0x7FFFu + ((u >> 16) & 1u)) >> 16);
}
__device__ __forceinline__ float bf2f(unsigned short u) {
  return __uint_as_float(((unsigned)u) << 16);
}
__device__ __forceinline__ float lo_f(unsigned int u) { return bf2f((unsigned short)(u & 0xFFFFu)); }
__device__ __forceinline__ float hi_f(unsigned int u) { return bf2f((unsigned short)(u >> 16)); }

// ---------------- weight pack helpers -> B-fragment bf16 layout ----------------
__device__ __forceinline__ void pack_one(const float* __restrict__ src,
                                         unsigned short* __restrict__ dst,
                                         int loc, int per, int N) {
  int lay = loc / per;
  int kn = loc - lay * per;
  int k = kn / N, n = kn - k * N;
  int kb = k >> 5, q = (k >> 3) & 3, j = k & 7, nt = n >> 4, c = n & 15;
  int NT = N >> 4;
  dst[(size_t)lay * per + (((kb * NT + nt) * 64 + (q * 16 + c)) * 8 + j)] = f2bf(src[loc]);
}

// dist_W padded pack: K=32 (rows 0..19 = dW, row 20 = db, rest 0), N=384
__device__ __forceinline__ void pack_dw(const float* __restrict__ dW,
                                        const float* __restrict__ db,
                                        unsigned short* __restrict__ dst, int loc) {
  int lay = loc / 12288;
  int kn = loc - lay * 12288;
  int k = kn / 384, n = kn - k * 384;
  float val = 0.0f;
  if (k < NRBF) val = dW[lay * NRBF * 384 + k * 384 + n];
  else if (k == NRBF) val = db[lay * 384 + n];
  int q = (k >> 3) & 3, j = k & 7, nt = n >> 4, c = n & 15;
  dst[(size_t)lay * 12288 + ((nt * 64 + (q * 16 + c)) * 8 + j)] = f2bf(val);
}

// ---------------- merged prep: blocks [0,PACK_BLOCKS) = weight pack; rest = geometry ----------------
__global__ __launch_bounds__(256) void prep_kernel(
    const float* __restrict__ msgW1, const float* __restrict__ msgW2,
    const float* __restrict__ updU, const float* __restrict__ updV,
    const float* __restrict__ updW1, const float* __restrict__ updW2,
    const float* __restrict__ rW1, const float* __restrict__ distW,
    const float* __restrict__ distb, unsigned short* __restrict__ dst,
    const float* __restrict__ xyz, const int* __restrict__ nbrs,
    float* __restrict__ unitv, unsigned short* __restrict__ rbf_bf,
    float* __restrict__ fcut,
    int* __restrict__ deg, int* __restrict__ slot_e, int* __restrict__ slot_j) {
  int b = blockIdx.x;
  if (b < PACK_BLOCKS) {
    int t = b * 256 + threadIdx.x;
    if (t < 49152) pack_one(msgW1, dst, t, 16384, 128);
    else if (t < 196608) pack_one(msgW2, dst + 49152, t - 49152, 49152, 384);
    else if (t < 245760) pack_one(updU, dst + 196608, t - 196608, 16384, 128);
    else if (t < 294912) pack_one(updV, dst + 245760, t - 245760, 16384, 128);
    else if (t < 393216) pack_one(updW1, dst + 294912, t - 294912, 32768, 128);
    else if (t < 540672) pack_one(updW2, dst + 393216, t - 393216, 49152, 384);
    else if (t < 548864) pack_one(rW1, dst + 540672, t - 540672, 8192, 64);
    else if (t < 585728) pack_dw(distW, distb, dst + 548864, t - 548864);
    return;
  }
  int e = (b - PACK_BLOCKS) * 256 + threadIdx.x;
  if (e >= NE) return;
  int i = nbrs[2 * e + 0], j = nbrs[2 * e + 1];
  float rx = xyz[3 * j + 0] - xyz[3 * i + 0];
  float ry = xyz[3 * j + 1] - xyz[3 * i + 1];
  float rz = xyz[3 * j + 2] - xyz[3 * i + 2];
  float d = sqrtf(rx * rx + ry * ry + rz * rz + EPS_F);
  if (d >= CUTOFF_F) return;
  float invd = 1.0f / d;
  float fc = 0.5f * (__cosf(PI_F * d / CUTOFF_F) + 1.0f);
  unitv[3 * e + 0] = rx * invd;
  unitv[3 * e + 1] = ry * invd;
  unitv[3 * e + 2] = rz * invd;
  fcut[e] = fc;
  float base = PI_F * d / CUTOFF_F;
  float sc = invd * fc;
#pragma unroll
  for (int k = 0; k < NRBF; k++)
    rbf_bf[(size_t)e * NRBF + k] = f2bf(__sinf((float)(k + 1) * base) * sc);
  int pos = atomicAdd(&deg[i], 1);
  if (pos < CAP) {
    slot_e[i * CAP + pos] = e;
    slot_j[i * CAP + pos] = j;
  }
}

// ---------------- layer-0 message MLP (fused s = emb[z] init); writes pv6 {phi, v=0} ----------------
__global__ __launch_bounds__(256) void msg0_mfma_kernel(
    const float* __restrict__ emb, const int* __restrict__ z, float* __restrict__ s_out,
    const unsigned short* __restrict__ pW1, const float* __restrict__ b1,
    const unsigned short* __restrict__ pW2, const float* __restrict__ b2,
    pv6* __restrict__ cmb) {
  __shared__ bf16x8 sA[4 * 64];
  __shared__ bf16x8 hA[4 * 64];
  int a0 = blockIdx.x * 16;
  int t = threadIdx.x;
  int lane = t & 63, w = t >> 6;
  {
    int kb = t >> 6, l = t & 63;
    int m = l & 15, q = l >> 4;
    int zi = z[a0 + m];
    const float* sp = emb + (size_t)zi * FDIM + kb * 32 + q * 8;
    float* so = s_out + (size_t)(a0 + m) * FDIM + kb * 32 + q * 8;
    bf16x8 c;
#pragma unroll
    for (int j = 0; j < 8; j++) {
      float v = sp[j];
      so[j] = v;
      c[j] = (short)f2bf(v);
    }
    sA[kb * 64 + l] = c;
  }
  __syncthreads();
  f32x4 accH[2];
#pragma unroll
  for (int t2 = 0; t2 < 2; t2++)
#pragma unroll
    for (int r = 0; r < 4; r++) accH[t2][r] = 0.0f;
  const bf16x8* W1f = (const bf16x8*)pW1;
#pragma unroll
  for (int kb = 0; kb < 4; kb++) {
    bf16x8 a = sA[kb * 64 + lane];
#pragma unroll
    for (int t2 = 0; t2 < 2; t2++) {
      bf16x8 b = W1f[(kb * 8 + 2 * w + t2) * 64 + lane];
      accH[t2] = __builtin_amdgcn_mfma_f32_16x16x32_bf16(a, b, accH[t2], 0, 0, 0);
    }
  }
  short* hs = (short*)hA;
#pragma unroll
  for (int t2 = 0; t2 < 2; t2++) {
    int n = w * 32 + t2 * 16 + (lane & 15);
    int kb = n >> 5, q = (n >> 3) & 3, j = n & 7;
    float bias = b1[n];
#pragma unroll
    for (int r = 0; r < 4; r++) {
      int m = (lane >> 4) * 4 + r;
      hs[(kb * 64 + q * 16 + m) * 8 + j] = (short)f2bf(silu_f(accH[t2][r] + bias));
    }
  }
  __syncthreads();
  f32x4 accP[3][2];
#pragma unroll
  for (int c3 = 0; c3 < 3; c3++)
#pragma unroll
    for (int t2 = 0; t2 < 2; t2++)
#pragma unroll
      for (int r = 0; r < 4; r++) accP[c3][t2][r] = 0.0f;
  const bf16x8* W2f = (const bf16x8*)pW2;
#pragma unroll
  for (int kb = 0; kb < 4; kb++) {
    bf16x8 a = hA[kb * 64 + lane];
#pragma unroll
    for (int c3 = 0; c3 < 3; c3++)
#pragma unroll
      for (int t2 = 0; t2 < 2; t2++) {
        bf16x8 b = W2f[(kb * 24 + c3 * 8 + 2 * w + t2) * 64 + lane];
        accP[c3][t2] = __builtin_amdgcn_mfma_f32_16x16x32_bf16(a, b, accP[c3][t2], 0, 0, 0);
      }
  }
#pragma unroll
  for (int t2 = 0; t2 < 2; t2++) {
    int g = (2 * w + t2) * 16 + (lane & 15);
    float bb0 = b2[g], bb1 = b2[FDIM + g], bb2 = b2[2 * FDIM + g];
#pragma unroll
    for (int r = 0; r < 4; r++) {
      int m = (lane >> 4) * 4 + r;
      unsigned p0 = f2bf(accP[0][t2][r] + bb0);
      unsigned p1 = f2bf(accP[1][t2][r] + bb1);
      unsigned p2 = f2bf(accP[2][t2][r] + bb2);
      pv6 rec;
      rec.u0 = p0 | (p1 << 16);
      rec.u1 = p2;
      rec.u2 = 0;
      cmb[(size_t)(a0 + m) * FDIM + g] = rec;
    }
  }
}

// ---------------- edge aggregation helpers ----------------
// A-fragment prefetch: lane's 8 rbf slots (+fcut at k==20) for edge c0+(lane&15).
__device__ __forceinline__ void afrag_load(const unsigned short* __restrict__ rbf_bf,
                                           const float* __restrict__ fcut,
                                           const int* l_e_all, int cnt, int c0,
                                           int m16, int q4,
                                           unsigned short apf[8], float* afc) {
#pragma unroll
  for (int j = 0; j < 8; j++) apf[j] = 0;
  *afc = 0.0f;
  int p = c0 + m16;
  if (p < cnt && q4 < 3) {
    int e = l_e_all[p];
    const unsigned short* rb = rbf_bf + (size_t)e * NRBF;
    if (q4 < 2) {
#pragma unroll
      for (int j = 0; j < 8; j++) apf[j] = rb[q4 * 8 + j];
    } else {
#pragma unroll
      for (int j = 0; j < 4; j++) apf[j] = rb[16 + j];
      *afc = fcut[e];
    }
  }
}

// ---------------- edge aggregation: transpose-free (consumer adopts MFMA C-layout) ----------------
// Wave w owns 16-edge chunks at c0 = 16*w, 16*w+32, ...  A-frag = rbf (edges x K32).
// MFMA gives lane: w_s[edge=q4*4+r][n=tile*16+n0].  Lane consumes its 4 edges at
// features g = fs*16+n0 (fs=0..7), c3 = tile/8 -> no w_lds transpose, no loop barriers.
// Invalid edges (p>=cnt) have zero rbf rows -> w_s=0, gathers clamped to valid slots.
// End: shfl_xor butterfly over edge-groups + one small LDS partial merge.
__global__ __launch_bounds__(128) void edge_kernel(
    const pv6* __restrict__ cmb, unsigned short* __restrict__ v_lin,
    float* __restrict__ s, const unsigned short* __restrict__ pDW,
    const int* __restrict__ deg, const int* __restrict__ slot_e,
    const int* __restrict__ slot_j, const unsigned short* __restrict__ rbf_bf,
    const float* __restrict__ fcut, const float* __restrict__ unitv) {
  __shared__ int l_e_all[CAP];
  __shared__ int l_j_all[CAP];
  __shared__ f32x4 part[2][128];
  int i = blockIdx.x;
  int t = threadIdx.x;
  int lane = t & 63, w = t >> 6;
  int cnt = deg[i];
  if (cnt > CAP) cnt = CAP;
  int base = i * CAP;
  if (t < cnt) {
    l_e_all[t] = slot_e[base + t];
    l_j_all[t] = slot_j[base + t];
  }
  __syncthreads();
  int n0 = lane & 15, q4 = lane >> 4;
  float accS[8], accV0[8], accV1[8], accV2[8];
#pragma unroll
  for (int fs = 0; fs < 8; fs++) { accS[fs] = 0.f; accV0[fs] = 0.f; accV1[fs] = 0.f; accV2[fs] = 0.f; }
  const bf16x8* Bf = (const bf16x8*)pDW;
  unsigned short apf[8];
  float afc = 0.0f;
  {
    int c00 = 16 * w;
    if (c00 < cnt) afrag_load(rbf_bf, fcut, l_e_all, cnt, c00, n0, q4, apf, &afc);
  }
  for (int c0 = 16 * w; c0 < cnt; c0 += 32) {
    // A fragment from prefetched registers
    bf16x8 a;
#pragma unroll
    for (int j = 0; j < 8; j++) a[j] = (short)apf[j];
    if (q4 == 2) a[4] = (short)f2bf(afc);
    // owned edges: p = c0 + q4*4 + r (clamped to a valid slot; w_s row = 0 kills them)
    size_t rowb[4];
    float ux[4], uy[4], uz[4];
#pragma unroll
    for (int r = 0; r < 4; r++) {
      int p = c0 + q4 * 4 + r;
      int ps = p < cnt ? p : c0;
      rowb[r] = (size_t)l_j_all[ps] * FDIM;
      int e = l_e_all[ps];
      ux[r] = unitv[3 * e + 0];
      uy[r] = unitv[3 * e + 1];
      uz[r] = unitv[3 * e + 2];
    }
    // prefetch next chunk's A-frag (lands during this chunk's compute)
    if (c0 + 32 < cnt) afrag_load(rbf_bf, fcut, l_e_all, cnt, c0 + 32, n0, q4, apf, &afc);
#pragma unroll
    for (int fs = 0; fs < 8; fs++) {
      // gathers issued first; MFMAs overlap their latency
      pv6 G[4];
#pragma unroll
      for (int r = 0; r < 4; r++) G[r] = cmb[rowb[r] + fs * 16 + n0];
      f32x4 z;
#pragma unroll
      for (int r = 0; r < 4; r++) z[r] = 0.0f;
      f32x4 w0 = __builtin_amdgcn_mfma_f32_16x16x32_bf16(a, Bf[fs * 64 + lane], z, 0, 0, 0);
      f32x4 w1 = __builtin_amdgcn_mfma_f32_16x16x32_bf16(a, Bf[(8 + fs) * 64 + lane], z, 0, 0, 0);
      f32x4 w2 = __builtin_amdgcn_mfma_f32_16x16x32_bf16(a, Bf[(16 + fs) * 64 + lane], z, 0, 0, 0);
#pragma unroll
      for (int r = 0; r < 4; r++) {
        pv6 R = G[r];
        float p0 = lo_f(R.u0), p1 = hi_f(R.u0), p2 = lo_f(R.u1);
        float vx = hi_f(R.u1), vy = lo_f(R.u2), vz = hi_f(R.u2);
        accS[fs] += p0 * w0[r];
        float i1 = p1 * w1[r], i2 = p2 * w2[r];
        accV0[fs] += i1 * vx + i2 * ux[r];
        accV1[fs] += i1 * vy + i2 * uy[r];
        accV2[fs] += i1 * vz + i2 * uz[r];
      }
    }
  }
  // butterfly reduce across edge-groups (lane bits 4,5); all replicas end identical
#pragma unroll
  for (int fs = 0; fs < 8; fs++) {
    accS[fs] += __shfl_xor(accS[fs], 16);  accS[fs] += __shfl_xor(accS[fs], 32);
    accV0[fs] += __shfl_xor(accV0[fs], 16); accV0[fs] += __shfl_xor(accV0[fs], 32);
    accV1[fs] += __shfl_xor(accV1[fs], 16); accV1[fs] += __shfl_xor(accV1[fs], 32);
    accV2[fs] += __shfl_xor(accV2[fs], 16); accV2[fs] += __shfl_xor(accV2[fs], 32);
  }
  // redundant same-value writes (4 replicas) keep indexing fully static
#pragma unroll
  for (int fs = 0; fs < 8; fs++) {
    f32x4 pr;
    pr[0] = accS[fs]; pr[1] = accV0[fs]; pr[2] = accV1[fs]; pr[3] = accV2[fs];
    part[w][fs * 16 + n0] = pr;
  }
  __syncthreads();
  {
    f32x4 q0 = part[0][t], q1 = part[1][t];
    float accs = q0[0] + q1[0];
    float v0 = q0[1] + q1[1];
    float v1 = q0[2] + q1[2];
    float v2 = q0[3] + q1[3];
    // own-atom v add: cmb v-halves are 0 for layer 0, so unconditional is correct
    pv6 RI = cmb[(size_t)i * FDIM + t];
    v0 += hi_f(RI.u1);
    v1 += lo_f(RI.u2);
    v2 += hi_f(RI.u2);
    unsigned short* vlo = v_lin + (size_t)i * F3;
    vlo[t] = f2bf(v0);
    vlo[FDIM + t] = f2bf(v1);
    vlo[2 * FDIM + t] = f2bf(v2);
    s[(size_t)i * FDIM + t] += accs;
  }
}

// ---------------- fused update (+ next-layer msg, or atom-energy readout) ----------------
// v_old re-read from vAf LDS (still live); u2 stored in s-epilogue; v0 kept in regs for msg epilogue.
__global__ __launch_bounds__(256) void upd_fused_kernel(
    float* __restrict__ s, const unsigned short* __restrict__ v_lin,
    pv6* __restrict__ cmb,
    const unsigned short* __restrict__ pU, const unsigned short* __restrict__ pV,
    const unsigned short* __restrict__ pW1, const float* __restrict__ b1,
    const unsigned short* __restrict__ pW2, const float* __restrict__ b2,
    int mode,
    const unsigned short* __restrict__ pMW1, const float* __restrict__ mb1,
    const unsigned short* __restrict__ pMW2, const float* __restrict__ mb2,
    const unsigned short* __restrict__ pRW1, const float* __restrict__ rb1,
    const float* __restrict__ rW2, const float* __restrict__ rb2,
    float* __restrict__ atom_e) {
  __shared__ bf16x8 vAf[3 * 4 * 64];
  __shared__ bf16x8 catA[8 * 64];
  __shared__ bf16x8 hA[4 * 64];
  __shared__ float red[4][16];
  int a0 = blockIdx.x * 16;
  int t = threadIdx.x;
  int lane = t & 63, w = t >> 6;
  {
    int l = t & 63, kb = (t >> 6) & 3;
    int m = l & 15, q = l >> 4;
#pragma unroll
    for (int rt = 0; rt < 3; rt++) {
      vAf[(rt * 4 + kb) * 64 + l] =
          *(const bf16x8*)(v_lin + (size_t)(a0 + m) * F3 + rt * FDIM + kb * 32 + q * 8);
    }
    const float* sp = s + (size_t)(a0 + m) * FDIM + kb * 32 + q * 8;
    bf16x8 c;
#pragma unroll
    for (int j = 0; j < 8; j++) c[j] = (short)f2bf(sp[j]);
    catA[kb * 64 + l] = c;
  }
  __syncthreads();
  f32x4 accU[3][2], accV[3][2];
#pragma unroll
  for (int rt = 0; rt < 3; rt++)
#pragma unroll
    for (int t2 = 0; t2 < 2; t2++)
#pragma unroll
      for (int r = 0; r < 4; r++) { accU[rt][t2][r] = 0.0f; accV[rt][t2][r] = 0.0f; }
  const bf16x8* Uf = (const bf16x8*)pU;
  const bf16x8* Vf = (const bf16x8*)pV;
#pragma unroll
  for (int kb = 0; kb < 4; kb++) {
    bf16x8 bu[2], bv[2];
#pragma unroll
    for (int t2 = 0; t2 < 2; t2++) {
      bu[t2] = Uf[(kb * 8 + 2 * w + t2) * 64 + lane];
      bv[t2] = Vf[(kb * 8 + 2 * w + t2) * 64 + lane];
    }
#pragma unroll
    for (int rt = 0; rt < 3; rt++) {
      bf16x8 a = vAf[(rt * 4 + kb) * 64 + lane];
#pragma unroll
      for (int t2 = 0; t2 < 2; t2++) {
        accU[rt][t2] = __builtin_amdgcn_mfma_f32_16x16x32_bf16(a, bu[t2], accU[rt][t2], 0, 0, 0);
        accV[rt][t2] = __builtin_amdgcn_mfma_f32_16x16x32_bf16(a, bv[t2], accV[rt][t2], 0, 0, 0);
      }
    }
  }
  short* cs = (short*)catA;
#pragma unroll
  for (int t2 = 0; t2 < 2; t2++) {
    int g = w * 32 + t2 * 16 + (lane & 15);
    int k = 128 + g;
    int kb = k >> 5, q = (k >> 3) & 3, j = k & 7;
#pragma unroll
    for (int r = 0; r < 4; r++) {
      int m = (lane >> 4) * 4 + r;
      float x0 = accV[0][t2][r], x1 = accV[1][t2][r], x2 = accV[2][t2][r];
      cs[(kb * 64 + q * 16 + m) * 8 + j] = (short)f2bf(sqrtf(x0 * x0 + x1 * x1 + x2 * x2 + EPS_F));
    }
  }
  __syncthreads();
  f32x4 accH[2];
#pragma unroll
  for (int t2 = 0; t2 < 2; t2++)
#pragma unroll
    for (int r = 0; r < 4; r++) accH[t2][r] = 0.0f;
  const bf16x8* W1f = (const bf16x8*)pW1;
#pragma unroll
  for (int kb = 0; kb < 8; kb++) {
    bf16x8 a = catA[kb * 64 + lane];
#pragma unroll
    for (int t2 = 0; t2 < 2; t2++) {
      bf16x8 b = W1f[(kb * 8 + 2 * w + t2) * 64 + lane];
      accH[t2] = __builtin_amdgcn_mfma_f32_16x16x32_bf16(a, b, accH[t2], 0, 0, 0);
    }
  }
  short* hs = (short*)hA;
#pragma unroll
  for (int t2 = 0; t2 < 2; t2++) {
    int n = w * 32 + t2 * 16 + (lane & 15);
    int kb = n >> 5, q = (n >> 3) & 3, j = n & 7;
    float bias = b1[n];
#pragma unroll
    for (int r = 0; r < 4; r++) {
      int m = (lane >> 4) * 4 + r;
      hs[(kb * 64 + q * 16 + m) * 8 + j] = (short)f2bf(silu_f(accH[t2][r] + bias));
    }
  }
  __syncthreads();
  f32x4 accA[3][2];
#pragma unroll
  for (int c3 = 0; c3 < 3; c3++)
#pragma unroll
    for (int t2 = 0; t2 < 2; t2++)
#pragma unroll
      for (int r = 0; r < 4; r++) accA[c3][t2][r] = 0.0f;
  const bf16x8* W2f = (const bf16x8*)pW2;
#pragma unroll
  for (int kb = 0; kb < 4; kb++) {
    bf16x8 a = hA[kb * 64 + lane];
#pragma unroll
    for (int c3 = 0; c3 < 3; c3++)
#pragma unroll
      for (int t2 = 0; t2 < 2; t2++) {
        bf16x8 b = W2f[(kb * 24 + c3 * 8 + 2 * w + t2) * 64 + lane];
        accA[c3][t2] = __builtin_amdgcn_mfma_f32_16x16x32_bf16(a, b, accA[c3][t2], 0, 0, 0);
      }
  }
  const short* vls = (const short*)vAf;  // v_old still live in LDS A-frag layout
  unsigned short v0keep[2][4];
#pragma unroll
  for (int t2 = 0; t2 < 2; t2++) {
    int g = w * 32 + t2 * 16 + (lane & 15);
    float bb0 = b2[g], bb1 = b2[FDIM + g], bb2 = b2[2 * FDIM + g];
    int kb = g >> 5, q = (g >> 3) & 3, j = g & 7;
#pragma unroll
    for (int r = 0; r < 4; r++) {
      int m = (lane >> 4) * 4 + r;
      int n = a0 + m;
      float a0v = accA[0][t2][r] + bb0;
      float a1v = accA[1][t2][r] + bb1;
      float a2v = accA[2][t2][r] + bb2;
      float dot = accU[0][t2][r] * accV[0][t2][r] + accU[1][t2][r] * accV[1][t2][r] +
                  accU[2][t2][r] * accV[2][t2][r];
      float s_new = s[(size_t)n * FDIM + g] + a1v * dot + a2v;
      if (mode == 0) {
        s[(size_t)n * FDIM + g] = s_new;
        float nv[3];
#pragma unroll
        for (int c = 0; c < 3; c++) {
          float vold = bf2f((unsigned short)vls[(((c * 4 + kb) * 64) + (q * 16 + m)) * 8 + j]);
          nv[c] = vold + a0v * accU[c][t2][r];
        }
        v0keep[t2][r] = f2bf(nv[0]);
        cmb[(size_t)n * FDIM + g].u2 = (unsigned)f2bf(nv[1]) | ((unsigned)f2bf(nv[2]) << 16);
      }
      cs[(kb * 64 + q * 16 + m) * 8 + j] = (short)f2bf(s_new);
    }
  }
  __syncthreads();
  if (mode == 0) {
    f32x4 accH2[2];
#pragma unroll
    for (int t2 = 0; t2 < 2; t2++)
#pragma unroll
      for (int r = 0; r < 4; r++) accH2[t2][r] = 0.0f;
    const bf16x8* MW1f = (const bf16x8*)pMW1;
#pragma unroll
    for (int kb = 0; kb < 4; kb++) {
      bf16x8 a = catA[kb * 64 + lane];
#pragma unroll
      for (int t2 = 0; t2 < 2; t2++) {
        bf16x8 b = MW1f[(kb * 8 + 2 * w + t2) * 64 + lane];
        accH2[t2] = __builtin_amdgcn_mfma_f32_16x16x32_bf16(a, b, accH2[t2], 0, 0, 0);
      }
    }
#pragma unroll
    for (int t2 = 0; t2 < 2; t2++) {
      int n = w * 32 + t2 * 16 + (lane & 15);
      int kb = n >> 5, q = (n >> 3) & 3, j = n & 7;
      float bias = mb1[n];
#pragma unroll
      for (int r = 0; r < 4; r++) {
        int m = (lane >> 4) * 4 + r;
        hs[(kb * 64 + q * 16 + m) * 8 + j] = (short)f2bf(silu_f(accH2[t2][r] + bias));
      }
    }
    __syncthreads();
    f32x4 accP[3][2];
#pragma unroll
    for (int c3 = 0; c3 < 3; c3++)
#pragma unroll
      for (int t2 = 0; t2 < 2; t2++)
#pragma unroll
        for (int r = 0; r < 4; r++) accP[c3][t2][r] = 0.0f;
    const bf16x8* MW2f = (const bf16x8*)pMW2;
#pragma unroll
    for (int kb = 0; kb < 4; kb++) {
      bf16x8 a = hA[kb * 64 + lane];
#pragma unroll
      for (int c3 = 0; c3 < 3; c3++)
#pragma unroll
        for (int t2 = 0; t2 < 2; t2++) {
          bf16x8 b = MW2f[(kb * 24 + c3 * 8 + 2 * w + t2) * 64 + lane];
          accP[c3][t2] = __builtin_amdgcn_mfma_f32_16x16x32_bf16(a, b, accP[c3][t2], 0, 0, 0);
        }
    }
#pragma unroll
    for (int t2 = 0; t2 < 2; t2++) {
      int g = (2 * w + t2) * 16 + (lane & 15);
      float bb0 = mb2[g], bb1 = mb2[FDIM + g], bb2v = mb2[2 * FDIM + g];
#pragma unroll
      for (int r = 0; r < 4; r++) {
        int m = (lane >> 4) * 4 + r;
        unsigned p0 = f2bf(accP[0][t2][r] + bb0);
        unsigned p1 = f2bf(accP[1][t2][r] + bb1);
        unsigned p2 = f2bf(accP[2][t2][r] + bb2v);
        pv6* rec = &cmb[(size_t)(a0 + m) * FDIM + g];
        rec->u0 = p0 | (p1 << 16);
        rec->u1 = p2 | ((unsigned)v0keep[t2][r] << 16);
      }
    }
  } else {
    f32x4 acc;
#pragma unroll
    for (int r = 0; r < 4; r++) acc[r] = 0.0f;
    const bf16x8* RW1f = (const bf16x8*)pRW1;
#pragma unroll
    for (int kb = 0; kb < 4; kb++) {
      bf16x8 a = catA[kb * 64 + lane];
      bf16x8 b = RW1f[(kb * 4 + w) * 64 + lane];
      acc = __builtin_amdgcn_mfma_f32_16x16x32_bf16(a, b, acc, 0, 0, 0);
    }
    int col = w * 16 + (lane & 15);
    float bias = rb1[col], w2v = rW2[col];
    float val[4];
#pragma unroll
    for (int r = 0; r < 4; r++) val[r] = silu_f(acc[r] + bias) * w2v;
#pragma unroll
    for (int off = 1; off < 16; off <<= 1)
#pragma unroll
      for (int r = 0; r < 4; r++) val[r] += __shfl_xor(val[r], off, 64);
    if ((lane & 15) == 0) {
#pragma unroll
      for (int r = 0; r < 4; r++) red[w][(lane >> 4) * 4 + r] = val[r];
    }
    __syncthreads();
    if (t < 16) {
      atom_e[a0 + t] = red[0][t] + red[1][t] + red[2][t] + red[3][t] + rb2[0];
    }
  }
}

// ---------------- molecule segment-sum: LDS partials, ~3 global atomics per block ----------------
__global__ __launch_bounds__(256) void mol_reduce_kernel(
    const float* __restrict__ atom_e, const int* __restrict__ mol_idx,
    float* __restrict__ out) {
  __shared__ float molsum[NMOLS];
  int t = threadIdx.x;
  if (t < NMOLS) molsum[t] = 0.0f;
  __syncthreads();
  int n = blockIdx.x * 256 + t;
  if (n < NA) atomicAdd(&molsum[mol_idx[n]], atom_e[n]);
  __syncthreads();
  if (t < NMOLS && molsum[t] != 0.0f) atomicAdd(&out[t], molsum[t]);
}

extern "C" void kernel_launch(void* const* d_in, const int* in_sizes, int n_in,
                              void* d_out, int out_size, void* d_ws, size_t ws_size,
                              hipStream_t stream) {
  const float* xyz = (const float*)d_in[0];
  const int* z = (const int*)d_in[1];
  const int* nbrs = (const int*)d_in[2];
  const int* mol = (const int*)d_in[3];
  const float* emb = (const float*)d_in[4];
  const float* msgW1 = (const float*)d_in[5];
  const float* msgb1 = (const float*)d_in[6];
  const float* msgW2 = (const float*)d_in[7];
  const float* msgb2 = (const float*)d_in[8];
  const float* distW = (const float*)d_in[9];
  const float* distb = (const float*)d_in[10];
  const float* updU = (const float*)d_in[11];
  const float* updV = (const float*)d_in[12];
  const float* updW1 = (const float*)d_in[13];
  const float* updb1 = (const float*)d_in[14];
  const float* updW2 = (const float*)d_in[15];
  const float* updb2 = (const float*)d_in[16];
  const float* rW1 = (const float*)d_in[17];
  const float* rb1 = (const float*)d_in[18];
  const float* rW2 = (const float*)d_in[19];
  const float* rb2 = (const float*)d_in[20];

  float* ws = (float*)d_ws;
  float* s = ws;      ws += (size_t)NA * FDIM;
  float* fcut = ws;   ws += (size_t)NE;
  float* unitv = ws;  ws += (size_t)NE * 3;
  float* atom_e = ws; ws += (size_t)NA;
  int* deg = (int*)ws;
  int* slot_e = deg + NA;
  int* slot_j = slot_e + NA * CAP;
  unsigned short* pk = (unsigned short*)(((uintptr_t)(slot_j + NA * CAP) + 15) & ~(uintptr_t)15);
  unsigned short* pMsgW1 = pk;                       // 49152
  unsigned short* pMsgW2 = pMsgW1 + 49152;           // 147456
  unsigned short* pUpdU  = pMsgW2 + 147456;          // 49152
  unsigned short* pUpdV  = pUpdU + 49152;            // 49152
  unsigned short* pUpdW1 = pUpdV + 49152;            // 98304
  unsigned short* pUpdW2 = pUpdW1 + 98304;           // 147456
  unsigned short* pRW1   = pUpdW2 + 147456;          // 8192
  unsigned short* pDW    = pRW1 + 8192;              // 3*12288
  unsigned short* rbf_bf = (unsigned short*)(((uintptr_t)(pDW + 36864) + 15) & ~(uintptr_t)15);
  unsigned short* after_rbf = rbf_bf + (size_t)NE * NRBF + 8;
  pv6* cmb = (pv6*)(((uintptr_t)after_rbf + 15) & ~(uintptr_t)15);           // NA*128 x 12B
  unsigned short* v_lin = (unsigned short*)(cmb + (size_t)NA * FDIM);        // NA*384

  hipMemsetAsync(deg, 0, NA * sizeof(int), stream);
  hipMemsetAsync(d_out, 0, NMOLS * sizeof(float), stream);

  prep_kernel<<<PACK_BLOCKS + NE / 256, 256, 0, stream>>>(
      msgW1, msgW2, updU, updV, updW1, updW2, rW1, distW, distb, pMsgW1,
      xyz, nbrs, unitv, rbf_bf, fcut, deg, slot_e, slot_j);
  msg0_mfma_kernel<<<NA / 16, 256, 0, stream>>>(emb, z, s, pMsgW1, msgb1, pMsgW2, msgb2, cmb);

  for (int l = 0; l < NLAYERS; l++) {
    edge_kernel<<<NA, 128, 0, stream>>>(cmb, v_lin, s,
                                        pDW + (size_t)l * 12288,
                                        deg, slot_e, slot_j, rbf_bf, fcut, unitv);
    int mode = (l == NLAYERS - 1) ? 1 : 0;
    int lnext = (l + 1 < NLAYERS) ? l + 1 : 0;
    upd_fused_kernel<<<NA / 16, 256, 0, stream>>>(
        s, v_lin, cmb, pUpdU + (size_t)l * 16384, pUpdV + (size_t)l * 16384,
        pUpdW1 + (size_t)l * 32768, updb1 + (size_t)l * FDIM,
        pUpdW2 + (size_t)l * 49152, updb2 + (size_t)l * F3,
        mode,
        pMsgW1 + (size_t)lnext * 16384, msgb1 + (size_t)lnext * FDIM,
        pMsgW2 + (size_t)lnext * 49152, msgb2 + (size_t)lnext * F3,
        pRW1, rb1, rW2, rb2, atom_e);
  }
  mol_reduce_kernel<<<(NA + 255) / 256, 256, 0, stream>>>(atom_e, mol, (float*)d_out);
}

// Round 6
// 315.371 us; speedup vs baseline: 1.6777x; 1.5557x over previous
//
#include <hip/hip_runtime.h>
#include <hip/hip_bf16.h>
#include <math.h>

#define NA 10000
#define NE 256000
#define FDIM 128
#define F3 384
#define NRBF 20
#define NLAYERS 3
#define NMOLS 100
#define CAP 96
#define MAXCH 6   // CAP/16 chunks per atom max
#define WROW 388  // padded w_lds row (bf16): conflict-free MFMA-C transpose (verified R6)
#define PACK_BLOCKS 2288  // 585728 / 256
#define CUTOFF_F 5.0f
#define EPS_F 1e-8f
#define PI_F 3.14159265358979323846f

typedef __attribute__((ext_vector_type(8))) short bf16x8;
typedef __attribute__((ext_vector_type(4))) float f32x4;

// 12-byte fused record: {phi0, phi1, phi2, v0, v1, v2} bf16
struct pv6 { unsigned int u0, u1, u2; };

__device__ __forceinline__ float silu_f(float x) { return x / (1.0f + __expf(-x)); }

__device__ __forceinline__ unsigned short f2bf(float x) {
  unsigned u = __float_as_uint(x);
  return (unsigned short)((u + 0x7FFFu + ((u >> 16) & 1u)) >> 16);
}
__device__ __forceinline__ float bf2f(unsigned short u) {
  return __uint_as_float(((unsigned)u) << 16);
}
__device__ __forceinline__ float lo_f(unsigned int u) { return bf2f((unsigned short)(u & 0xFFFFu)); }
__device__ __forceinline__ float hi_f(unsigned int u) { return bf2f((unsigned short)(u >> 16)); }

// ---------------- weight pack helpers -> B-fragment bf16 layout ----------------
__device__ __forceinline__ void pack_one(const float* __restrict__ src,
                                         unsigned short* __restrict__ dst,
                                         int loc, int per, int N) {
  int lay = loc / per;
  int kn = loc - lay * per;
  int k = kn / N, n = kn - k * N;
  int kb = k >> 5, q = (k >> 3) & 3, j = k & 7, nt = n >> 4, c = n & 15;
  int NT = N >> 4;
  dst[(size_t)lay * per + (((kb * NT + nt) * 64 + (q * 16 + c)) * 8 + j)] = f2bf(src[loc]);
}

// dist_W padded pack: K=32 (rows 0..19 = dW, row 20 = db, rest 0), N=384
__device__ __forceinline__ void pack_dw(const float* __restrict__ dW,
                                        const float* __restrict__ db,
                                        unsigned short* __restrict__ dst, int loc) {
  int lay = loc / 12288;
  int kn = loc - lay * 12288;
  int k = kn / 384, n = kn - k * 384;
  float val = 0.0f;
  if (k < NRBF) val = dW[lay * NRBF * 384 + k * 384 + n];
  else if (k == NRBF) val = db[lay * 384 + n];
  int q = (k >> 3) & 3, j = k & 7, nt = n >> 4, c = n & 15;
  dst[(size_t)lay * 12288 + ((nt * 64 + (q * 16 + c)) * 8 + j)] = f2bf(val);
}

// ---------------- merged prep: blocks [0,PACK_BLOCKS) = weight pack; rest = geometry ----------------
__global__ __launch_bounds__(256) void prep_kernel(
    const float* __restrict__ msgW1, const float* __restrict__ msgW2,
    const float* __restrict__ updU, const float* __restrict__ updV,
    const float* __restrict__ updW1, const float* __restrict__ updW2,
    const float* __restrict__ rW1, const float* __restrict__ distW,
    const float* __restrict__ distb, unsigned short* __restrict__ dst,
    const float* __restrict__ xyz, const int* __restrict__ nbrs,
    float* __restrict__ unitv, unsigned short* __restrict__ rbf_bf,
    float* __restrict__ fcut,
    int* __restrict__ deg, int* __restrict__ slot_e, int* __restrict__ slot_j) {
  int b = blockIdx.x;
  if (b < PACK_BLOCKS) {
    int t = b * 256 + threadIdx.x;
    if (t < 49152) pack_one(msgW1, dst, t, 16384, 128);
    else if (t < 196608) pack_one(msgW2, dst + 49152, t - 49152, 49152, 384);
    else if (t < 245760) pack_one(updU, dst + 196608, t - 196608, 16384, 128);
    else if (t < 294912) pack_one(updV, dst + 245760, t - 245760, 16384, 128);
    else if (t < 393216) pack_one(updW1, dst + 294912, t - 294912, 32768, 128);
    else if (t < 540672) pack_one(updW2, dst + 393216, t - 393216, 49152, 384);
    else if (t < 548864) pack_one(rW1, dst + 540672, t - 540672, 8192, 64);
    else if (t < 585728) pack_dw(distW, distb, dst + 548864, t - 548864);
    return;
  }
  int e = (b - PACK_BLOCKS) * 256 + threadIdx.x;
  if (e >= NE) return;
  int i = nbrs[2 * e + 0], j = nbrs[2 * e + 1];
  float rx = xyz[3 * j + 0] - xyz[3 * i + 0];
  float ry = xyz[3 * j + 1] - xyz[3 * i + 1];
  float rz = xyz[3 * j + 2] - xyz[3 * i + 2];
  float d = sqrtf(rx * rx + ry * ry + rz * rz + EPS_F);
  if (d >= CUTOFF_F) return;
  float invd = 1.0f / d;
  float fc = 0.5f * (__cosf(PI_F * d / CUTOFF_F) + 1.0f);
  unitv[3 * e + 0] = rx * invd;
  unitv[3 * e + 1] = ry * invd;
  unitv[3 * e + 2] = rz * invd;
  fcut[e] = fc;
  float base = PI_F * d / CUTOFF_F;
  float sc = invd * fc;
#pragma unroll
  for (int k = 0; k < NRBF; k++)
    rbf_bf[(size_t)e * NRBF + k] = f2bf(__sinf((float)(k + 1) * base) * sc);
  int pos = atomicAdd(&deg[i], 1);
  if (pos < CAP) {
    slot_e[i * CAP + pos] = e;
    slot_j[i * CAP + pos] = j;
  }
}

// ---------------- layer-0 message MLP (fused s = emb[z] init); writes pv6 {phi, v=0} ----------------
__global__ __launch_bounds__(256) void msg0_mfma_kernel(
    const float* __restrict__ emb, const int* __restrict__ z, float* __restrict__ s_out,
    const unsigned short* __restrict__ pW1, const float* __restrict__ b1,
    const unsigned short* __restrict__ pW2, const float* __restrict__ b2,
    pv6* __restrict__ cmb) {
  __shared__ bf16x8 sA[4 * 64];
  __shared__ bf16x8 hA[4 * 64];
  int a0 = blockIdx.x * 16;
  int t = threadIdx.x;
  int lane = t & 63, w = t >> 6;
  {
    int kb = t >> 6, l = t & 63;
    int m = l & 15, q = l >> 4;
    int zi = z[a0 + m];
    const float* sp = emb + (size_t)zi * FDIM + kb * 32 + q * 8;
    float* so = s_out + (size_t)(a0 + m) * FDIM + kb * 32 + q * 8;
    bf16x8 c;
#pragma unroll
    for (int j = 0; j < 8; j++) {
      float v = sp[j];
      so[j] = v;
      c[j] = (short)f2bf(v);
    }
    sA[kb * 64 + l] = c;
  }
  __syncthreads();
  f32x4 accH[2];
#pragma unroll
  for (int t2 = 0; t2 < 2; t2++)
#pragma unroll
    for (int r = 0; r < 4; r++) accH[t2][r] = 0.0f;
  const bf16x8* W1f = (const bf16x8*)pW1;
#pragma unroll
  for (int kb = 0; kb < 4; kb++) {
    bf16x8 a = sA[kb * 64 + lane];
#pragma unroll
    for (int t2 = 0; t2 < 2; t2++) {
      bf16x8 b = W1f[(kb * 8 + 2 * w + t2) * 64 + lane];
      accH[t2] = __builtin_amdgcn_mfma_f32_16x16x32_bf16(a, b, accH[t2], 0, 0, 0);
    }
  }
  short* hs = (short*)hA;
#pragma unroll
  for (int t2 = 0; t2 < 2; t2++) {
    int n = w * 32 + t2 * 16 + (lane & 15);
    int kb = n >> 5, q = (n >> 3) & 3, j = n & 7;
    float bias = b1[n];
#pragma unroll
    for (int r = 0; r < 4; r++) {
      int m = (lane >> 4) * 4 + r;
      hs[(kb * 64 + q * 16 + m) * 8 + j] = (short)f2bf(silu_f(accH[t2][r] + bias));
    }
  }
  __syncthreads();
  f32x4 accP[3][2];
#pragma unroll
  for (int c3 = 0; c3 < 3; c3++)
#pragma unroll
    for (int t2 = 0; t2 < 2; t2++)
#pragma unroll
      for (int r = 0; r < 4; r++) accP[c3][t2][r] = 0.0f;
  const bf16x8* W2f = (const bf16x8*)pW2;
#pragma unroll
  for (int kb = 0; kb < 4; kb++) {
    bf16x8 a = hA[kb * 64 + lane];
#pragma unroll
    for (int c3 = 0; c3 < 3; c3++)
#pragma unroll
      for (int t2 = 0; t2 < 2; t2++) {
        bf16x8 b = W2f[(kb * 24 + c3 * 8 + 2 * w + t2) * 64 + lane];
        accP[c3][t2] = __builtin_amdgcn_mfma_f32_16x16x32_bf16(a, b, accP[c3][t2], 0, 0, 0);
      }
  }
#pragma unroll
  for (int t2 = 0; t2 < 2; t2++) {
    int g = (2 * w + t2) * 16 + (lane & 15);
    float bb0 = b2[g], bb1 = b2[FDIM + g], bb2 = b2[2 * FDIM + g];
#pragma unroll
    for (int r = 0; r < 4; r++) {
      int m = (lane >> 4) * 4 + r;
      unsigned p0 = f2bf(accP[0][t2][r] + bb0);
      unsigned p1 = f2bf(accP[1][t2][r] + bb1);
      unsigned p2 = f2bf(accP[2][t2][r] + bb2);
      pv6 rec;
      rec.u0 = p0 | (p1 << 16);
      rec.u1 = p2;
      rec.u2 = 0;
      cmb[(size_t)(a0 + m) * FDIM + g] = rec;
    }
  }
}

// ---------------- edge aggregation: one block per (atom, 16-edge chunk) ----------------
// Grid = NA*MAXCH; block b -> atom b%NA, chunk b/NA. Empty chunks exit in 2 loads.
// Body = proven R0 phase: slots/l_u -> sync -> reg A-frag -> 12 MFMA/wave -> sync ->
// 16-edge gather/process. Partials accumulate via atomicAdd into float s and v_acc
// (v_acc pre-seeded with v_prev by upd_fused / memset for layer 0).
__global__ __launch_bounds__(128) void edge_chunk_kernel(
    const pv6* __restrict__ cmb, float* __restrict__ v_acc,
    float* __restrict__ s, const unsigned short* __restrict__ pDW,
    const int* __restrict__ deg, const int* __restrict__ slot_e,
    const int* __restrict__ slot_j, const unsigned short* __restrict__ rbf_bf,
    const float* __restrict__ fcut, const float* __restrict__ unitv) {
  __shared__ __align__(16) unsigned short w_lds[16][WROW];
  __shared__ float l_u[16][3];
  __shared__ int l_e[16];
  __shared__ int l_j[16];
  int b = blockIdx.x;
  int i = b % NA, c = b / NA;
  int off = c * 16;
  int cnt = deg[i];
  if (cnt > CAP) cnt = CAP;
  if (off >= cnt) return;
  int ccnt = cnt - off;
  if (ccnt > 16) ccnt = 16;
  int t = threadIdx.x;
  int lane = t & 63, w = t >> 6;
  int base = i * CAP + off;
  if (t < 16) {
    int p = base + (t < ccnt ? t : 0);  // clamp: slots beyond cnt are uninitialized
    int e = slot_e[p];
    l_e[t] = e;
    l_j[t] = slot_j[p];
    l_u[t][0] = unitv[3 * e + 0];
    l_u[t][1] = unitv[3 * e + 1];
    l_u[t][2] = unitv[3 * e + 2];
  }
  __syncthreads();
  // A-fragment in registers (both waves identical): lane (m16,q4) = edge off+m16, k-slice q4
  int m16 = lane & 15, q4 = lane >> 4;
  bf16x8 a;
#pragma unroll
  for (int j = 0; j < 8; j++) a[j] = 0;
  if (q4 < 3 && m16 < ccnt) {
    int e = l_e[m16];
    const unsigned short* rb = rbf_bf + (size_t)e * NRBF;
    if (q4 < 2) {
#pragma unroll
      for (int j = 0; j < 8; j++) a[j] = (short)rb[q4 * 8 + j];
    } else {
#pragma unroll
      for (int j = 0; j < 4; j++) a[j] = (short)rb[16 + j];
      a[4] = (short)f2bf(fcut[e]);
    }
  }
  const bf16x8* Bf = (const bf16x8*)pDW;
  {
    int mrow = q4 * 4;
#pragma unroll
    for (int tt = 0; tt < 12; tt++) {
      int nt = 12 * w + tt;
      f32x4 acc;
#pragma unroll
      for (int r = 0; r < 4; r++) acc[r] = 0.0f;
      acc = __builtin_amdgcn_mfma_f32_16x16x32_bf16(a, Bf[nt * 64 + lane], acc, 0, 0, 0);
      int n = nt * 16 + m16;
#pragma unroll
      for (int r = 0; r < 4; r++) w_lds[mrow + r][n] = f2bf(acc[r]);
    }
  }
  __syncthreads();
  int f = t;
  float acc_s = 0.f, av0 = 0.f, av1 = 0.f, av2 = 0.f;
  int pp = 0;
  for (; pp + 4 <= ccnt; pp += 4) {
    pv6 R[4];
#pragma unroll
    for (int u = 0; u < 4; u++) R[u] = cmb[(size_t)l_j[pp + u] * FDIM + f];
#pragma unroll
    for (int u = 0; u < 4; u++) {
      float p0 = lo_f(R[u].u0), p1 = hi_f(R[u].u0), p2 = lo_f(R[u].u1);
      float v0 = hi_f(R[u].u1), v1 = lo_f(R[u].u2), v2 = hi_f(R[u].u2);
      float w0 = bf2f(w_lds[pp + u][f]), w1 = bf2f(w_lds[pp + u][FDIM + f]),
            w2 = bf2f(w_lds[pp + u][2 * FDIM + f]);
      acc_s += p0 * w0;
      float i1 = p1 * w1, i2 = p2 * w2;
      av0 += i1 * v0 + i2 * l_u[pp + u][0];
      av1 += i1 * v1 + i2 * l_u[pp + u][1];
      av2 += i1 * v2 + i2 * l_u[pp + u][2];
    }
  }
  for (; pp < ccnt; pp++) {
    pv6 R0 = cmb[(size_t)l_j[pp] * FDIM + f];
    float p0 = lo_f(R0.u0), p1 = hi_f(R0.u0), p2 = lo_f(R0.u1);
    float v0 = hi_f(R0.u1), v1 = lo_f(R0.u2), v2 = hi_f(R0.u2);
    float w0 = bf2f(w_lds[pp][f]), w1 = bf2f(w_lds[pp][FDIM + f]),
          w2 = bf2f(w_lds[pp][2 * FDIM + f]);
    acc_s += p0 * w0;
    float i1 = p1 * w1, i2 = p2 * w2;
    av0 += i1 * v0 + i2 * l_u[pp][0];
    av1 += i1 * v1 + i2 * l_u[pp][1];
    av2 += i1 * v2 + i2 * l_u[pp][2];
  }
  atomicAdd(&s[(size_t)i * FDIM + f], acc_s);
  atomicAdd(&v_acc[((size_t)i * 3 + 0) * FDIM + f], av0);
  atomicAdd(&v_acc[((size_t)i * 3 + 1) * FDIM + f], av1);
  atomicAdd(&v_acc[((size_t)i * 3 + 2) * FDIM + f], av2);
}

// ---------------- fused update (+ next-layer msg, or atom-energy readout) ----------------
// v in/out through float v_acc (holds v_prev + edge sums on entry; v_new written back
// for the next layer's edge pass). v_old re-read from vAf LDS; v0 kept for msg epilogue.
__global__ __launch_bounds__(256) void upd_fused_kernel(
    float* __restrict__ s, float* __restrict__ v_acc,
    pv6* __restrict__ cmb,
    const unsigned short* __restrict__ pU, const unsigned short* __restrict__ pV,
    const unsigned short* __restrict__ pW1, const float* __restrict__ b1,
    const unsigned short* __restrict__ pW2, const float* __restrict__ b2,
    int mode,
    const unsigned short* __restrict__ pMW1, const float* __restrict__ mb1,
    const unsigned short* __restrict__ pMW2, const float* __restrict__ mb2,
    const unsigned short* __restrict__ pRW1, const float* __restrict__ rb1,
    const float* __restrict__ rW2, const float* __restrict__ rb2,
    float* __restrict__ atom_e) {
  __shared__ bf16x8 vAf[3 * 4 * 64];
  __shared__ bf16x8 catA[8 * 64];
  __shared__ bf16x8 hA[4 * 64];
  __shared__ float red[4][16];
  int a0 = blockIdx.x * 16;
  int t = threadIdx.x;
  int lane = t & 63, w = t >> 6;
  {
    int l = t & 63, kb = (t >> 6) & 3;
    int m = l & 15, q = l >> 4;
#pragma unroll
    for (int rt = 0; rt < 3; rt++) {
      const float* vp = v_acc + ((size_t)(a0 + m) * 3 + rt) * FDIM + kb * 32 + q * 8;
      f32x4 va = *(const f32x4*)vp;
      f32x4 vb = *(const f32x4*)(vp + 4);
      bf16x8 cvv;
#pragma unroll
      for (int j = 0; j < 4; j++) {
        cvv[j] = (short)f2bf(va[j]);
        cvv[4 + j] = (short)f2bf(vb[j]);
      }
      vAf[(rt * 4 + kb) * 64 + l] = cvv;
    }
    const float* sp = s + (size_t)(a0 + m) * FDIM + kb * 32 + q * 8;
    bf16x8 c;
#pragma unroll
    for (int j = 0; j < 8; j++) c[j] = (short)f2bf(sp[j]);
    catA[kb * 64 + l] = c;
  }
  __syncthreads();
  f32x4 accU[3][2], accV[3][2];
#pragma unroll
  for (int rt = 0; rt < 3; rt++)
#pragma unroll
    for (int t2 = 0; t2 < 2; t2++)
#pragma unroll
      for (int r = 0; r < 4; r++) { accU[rt][t2][r] = 0.0f; accV[rt][t2][r] = 0.0f; }
  const bf16x8* Uf = (const bf16x8*)pU;
  const bf16x8* Vf = (const bf16x8*)pV;
#pragma unroll
  for (int kb = 0; kb < 4; kb++) {
    bf16x8 bu[2], bv[2];
#pragma unroll
    for (int t2 = 0; t2 < 2; t2++) {
      bu[t2] = Uf[(kb * 8 + 2 * w + t2) * 64 + lane];
      bv[t2] = Vf[(kb * 8 + 2 * w + t2) * 64 + lane];
    }
#pragma unroll
    for (int rt = 0; rt < 3; rt++) {
      bf16x8 a = vAf[(rt * 4 + kb) * 64 + lane];
#pragma unroll
      for (int t2 = 0; t2 < 2; t2++) {
        accU[rt][t2] = __builtin_amdgcn_mfma_f32_16x16x32_bf16(a, bu[t2], accU[rt][t2], 0, 0, 0);
        accV[rt][t2] = __builtin_amdgcn_mfma_f32_16x16x32_bf16(a, bv[t2], accV[rt][t2], 0, 0, 0);
      }
    }
  }
  short* cs = (short*)catA;
#pragma unroll
  for (int t2 = 0; t2 < 2; t2++) {
    int g = w * 32 + t2 * 16 + (lane & 15);
    int k = 128 + g;
    int kb = k >> 5, q = (k >> 3) & 3, j = k & 7;
#pragma unroll
    for (int r = 0; r < 4; r++) {
      int m = (lane >> 4) * 4 + r;
      float x0 = accV[0][t2][r], x1 = accV[1][t2][r], x2 = accV[2][t2][r];
      cs[(kb * 64 + q * 16 + m) * 8 + j] = (short)f2bf(sqrtf(x0 * x0 + x1 * x1 + x2 * x2 + EPS_F));
    }
  }
  __syncthreads();
  f32x4 accH[2];
#pragma unroll
  for (int t2 = 0; t2 < 2; t2++)
#pragma unroll
    for (int r = 0; r < 4; r++) accH[t2][r] = 0.0f;
  const bf16x8* W1f = (const bf16x8*)pW1;
#pragma unroll
  for (int kb = 0; kb < 8; kb++) {
    bf16x8 a = catA[kb * 64 + lane];
#pragma unroll
    for (int t2 = 0; t2 < 2; t2++) {
      bf16x8 b = W1f[(kb * 8 + 2 * w + t2) * 64 + lane];
      accH[t2] = __builtin_amdgcn_mfma_f32_16x16x32_bf16(a, b, accH[t2], 0, 0, 0);
    }
  }
  short* hs = (short*)hA;
#pragma unroll
  for (int t2 = 0; t2 < 2; t2++) {
    int n = w * 32 + t2 * 16 + (lane & 15);
    int kb = n >> 5, q = (n >> 3) & 3, j = n & 7;
    float bias = b1[n];
#pragma unroll
    for (int r = 0; r < 4; r++) {
      int m = (lane >> 4) * 4 + r;
      hs[(kb * 64 + q * 16 + m) * 8 + j] = (short)f2bf(silu_f(accH[t2][r] + bias));
    }
  }
  __syncthreads();
  f32x4 accA[3][2];
#pragma unroll
  for (int c3 = 0; c3 < 3; c3++)
#pragma unroll
    for (int t2 = 0; t2 < 2; t2++)
#pragma unroll
      for (int r = 0; r < 4; r++) accA[c3][t2][r] = 0.0f;
  const bf16x8* W2f = (const bf16x8*)pW2;
#pragma unroll
  for (int kb = 0; kb < 4; kb++) {
    bf16x8 a = hA[kb * 64 + lane];
#pragma unroll
    for (int c3 = 0; c3 < 3; c3++)
#pragma unroll
      for (int t2 = 0; t2 < 2; t2++) {
        bf16x8 b = W2f[(kb * 24 + c3 * 8 + 2 * w + t2) * 64 + lane];
        accA[c3][t2] = __builtin_amdgcn_mfma_f32_16x16x32_bf16(a, b, accA[c3][t2], 0, 0, 0);
      }
  }
  const short* vls = (const short*)vAf;  // v_old still live in LDS A-frag layout
  unsigned short v0keep[2][4];
#pragma unroll
  for (int t2 = 0; t2 < 2; t2++) {
    int g = w * 32 + t2 * 16 + (lane & 15);
    float bb0 = b2[g], bb1 = b2[FDIM + g], bb2 = b2[2 * FDIM + g];
    int kb = g >> 5, q = (g >> 3) & 3, j = g & 7;
#pragma unroll
    for (int r = 0; r < 4; r++) {
      int m = (lane >> 4) * 4 + r;
      int n = a0 + m;
      float a0v = accA[0][t2][r] + bb0;
      float a1v = accA[1][t2][r] + bb1;
      float a2v = accA[2][t2][r] + bb2;
      float dot = accU[0][t2][r] * accV[0][t2][r] + accU[1][t2][r] * accV[1][t2][r] +
                  accU[2][t2][r] * accV[2][t2][r];
      float s_new = s[(size_t)n * FDIM + g] + a1v * dot + a2v;
      if (mode == 0) {
        s[(size_t)n * FDIM + g] = s_new;
        float nv[3];
#pragma unroll
        for (int c = 0; c < 3; c++) {
          float vold = bf2f((unsigned short)vls[(((c * 4 + kb) * 64) + (q * 16 + m)) * 8 + j]);
          nv[c] = vold + a0v * accU[c][t2][r];
        }
        v0keep[t2][r] = f2bf(nv[0]);
        cmb[(size_t)n * FDIM + g].u2 = (unsigned)f2bf(nv[1]) | ((unsigned)f2bf(nv[2]) << 16);
        // seed v_acc with v_prev for the next layer's edge accumulation
        v_acc[((size_t)n * 3 + 0) * FDIM + g] = nv[0];
        v_acc[((size_t)n * 3 + 1) * FDIM + g] = nv[1];
        v_acc[((size_t)n * 3 + 2) * FDIM + g] = nv[2];
      }
      cs[(kb * 64 + q * 16 + m) * 8 + j] = (short)f2bf(s_new);
    }
  }
  __syncthreads();
  if (mode == 0) {
    f32x4 accH2[2];
#pragma unroll
    for (int t2 = 0; t2 < 2; t2++)
#pragma unroll
      for (int r = 0; r < 4; r++) accH2[t2][r] = 0.0f;
    const bf16x8* MW1f = (const bf16x8*)pMW1;
#pragma unroll
    for (int kb = 0; kb < 4; kb++) {
      bf16x8 a = catA[kb * 64 + lane];
#pragma unroll
      for (int t2 = 0; t2 < 2; t2++) {
        bf16x8 b = MW1f[(kb * 8 + 2 * w + t2) * 64 + lane];
        accH2[t2] = __builtin_amdgcn_mfma_f32_16x16x32_bf16(a, b, accH2[t2], 0, 0, 0);
      }
    }
#pragma unroll
    for (int t2 = 0; t2 < 2; t2++) {
      int n = w * 32 + t2 * 16 + (lane & 15);
      int kb = n >> 5, q = (n >> 3) & 3, j = n & 7;
      float bias = mb1[n];
#pragma unroll
      for (int r = 0; r < 4; r++) {
        int m = (lane >> 4) * 4 + r;
        hs[(kb * 64 + q * 16 + m) * 8 + j] = (short)f2bf(silu_f(accH2[t2][r] + bias));
      }
    }
    __syncthreads();
    f32x4 accP[3][2];
#pragma unroll
    for (int c3 = 0; c3 < 3; c3++)
#pragma unroll
      for (int t2 = 0; t2 < 2; t2++)
#pragma unroll
        for (int r = 0; r < 4; r++) accP[c3][t2][r] = 0.0f;
    const bf16x8* MW2f = (const bf16x8*)pMW2;
#pragma unroll
    for (int kb = 0; kb < 4; kb++) {
      bf16x8 a = hA[kb * 64 + lane];
#pragma unroll
      for (int c3 = 0; c3 < 3; c3++)
#pragma unroll
        for (int t2 = 0; t2 < 2; t2++) {
          bf16x8 b = MW2f[(kb * 24 + c3 * 8 + 2 * w + t2) * 64 + lane];
          accP[c3][t2] = __builtin_amdgcn_mfma_f32_16x16x32_bf16(a, b, accP[c3][t2], 0, 0, 0);
        }
    }
#pragma unroll
    for (int t2 = 0; t2 < 2; t2++) {
      int g = (2 * w + t2) * 16 + (lane & 15);
      float bb0 = mb2[g], bb1 = mb2[FDIM + g], bb2v = mb2[2 * FDIM + g];
#pragma unroll
      for (int r = 0; r < 4; r++) {
        int m = (lane >> 4) * 4 + r;
        unsigned p0 = f2bf(accP[0][t2][r] + bb0);
        unsigned p1 = f2bf(accP[1][t2][r] + bb1);
        unsigned p2 = f2bf(accP[2][t2][r] + bb2v);
        pv6* rec = &cmb[(size_t)(a0 + m) * FDIM + g];
        rec->u0 = p0 | (p1 << 16);
        rec->u1 = p2 | ((unsigned)v0keep[t2][r] << 16);
      }
    }
  } else {
    f32x4 acc;
#pragma unroll
    for (int r = 0; r < 4; r++) acc[r] = 0.0f;
    const bf16x8* RW1f = (const bf16x8*)pRW1;
#pragma unroll
    for (int kb = 0; kb < 4; kb++) {
      bf16x8 a = catA[kb * 64 + lane];
      bf16x8 b = RW1f[(kb * 4 + w) * 64 + lane];
      acc = __builtin_amdgcn_mfma_f32_16x16x32_bf16(a, b, acc, 0, 0, 0);
    }
    int col = w * 16 + (lane & 15);
    float bias = rb1[col], w2v = rW2[col];
    float val[4];
#pragma unroll
    for (int r = 0; r < 4; r++) val[r] = silu_f(acc[r] + bias) * w2v;
#pragma unroll
    for (int off = 1; off < 16; off <<= 1)
#pragma unroll
      for (int r = 0; r < 4; r++) val[r] += __shfl_xor(val[r], off, 64);
    if ((lane & 15) == 0) {
#pragma unroll
      for (int r = 0; r < 4; r++) red[w][(lane >> 4) * 4 + r] = val[r];
    }
    __syncthreads();
    if (t < 16) {
      atom_e[a0 + t] = red[0][t] + red[1][t] + red[2][t] + red[3][t] + rb2[0];
    }
  }
}

// ---------------- molecule segment-sum: LDS partials, ~3 global atomics per block ----------------
__global__ __launch_bounds__(256) void mol_reduce_kernel(
    const float* __restrict__ atom_e, const int* __restrict__ mol_idx,
    float* __restrict__ out) {
  __shared__ float molsum[NMOLS];
  int t = threadIdx.x;
  if (t < NMOLS) molsum[t] = 0.0f;
  __syncthreads();
  int n = blockIdx.x * 256 + t;
  if (n < NA) atomicAdd(&molsum[mol_idx[n]], atom_e[n]);
  __syncthreads();
  if (t < NMOLS && molsum[t] != 0.0f) atomicAdd(&out[t], molsum[t]);
}

extern "C" void kernel_launch(void* const* d_in, const int* in_sizes, int n_in,
                              void* d_out, int out_size, void* d_ws, size_t ws_size,
                              hipStream_t stream) {
  const float* xyz = (const float*)d_in[0];
  const int* z = (const int*)d_in[1];
  const int* nbrs = (const int*)d_in[2];
  const int* mol = (const int*)d_in[3];
  const float* emb = (const float*)d_in[4];
  const float* msgW1 = (const float*)d_in[5];
  const float* msgb1 = (const float*)d_in[6];
  const float* msgW2 = (const float*)d_in[7];
  const float* msgb2 = (const float*)d_in[8];
  const float* distW = (const float*)d_in[9];
  const float* distb = (const float*)d_in[10];
  const float* updU = (const float*)d_in[11];
  const float* updV = (const float*)d_in[12];
  const float* updW1 = (const float*)d_in[13];
  const float* updb1 = (const float*)d_in[14];
  const float* updW2 = (const float*)d_in[15];
  const float* updb2 = (const float*)d_in[16];
  const float* rW1 = (const float*)d_in[17];
  const float* rb1 = (const float*)d_in[18];
  const float* rW2 = (const float*)d_in[19];
  const float* rb2 = (const float*)d_in[20];

  float* ws = (float*)d_ws;
  float* s = ws;      ws += (size_t)NA * FDIM;
  float* fcut = ws;   ws += (size_t)NE;
  float* unitv = ws;  ws += (size_t)NE * 3;
  float* atom_e = ws; ws += (size_t)NA;
  int* deg = (int*)ws;
  int* slot_e = deg + NA;
  int* slot_j = slot_e + NA * CAP;
  unsigned short* pk = (unsigned short*)(((uintptr_t)(slot_j + NA * CAP) + 15) & ~(uintptr_t)15);
  unsigned short* pMsgW1 = pk;                       // 49152
  unsigned short* pMsgW2 = pMsgW1 + 49152;           // 147456
  unsigned short* pUpdU  = pMsgW2 + 147456;          // 49152
  unsigned short* pUpdV  = pUpdU + 49152;            // 49152
  unsigned short* pUpdW1 = pUpdV + 49152;            // 98304
  unsigned short* pUpdW2 = pUpdW1 + 98304;           // 147456
  unsigned short* pRW1   = pUpdW2 + 147456;          // 8192
  unsigned short* pDW    = pRW1 + 8192;              // 3*12288
  unsigned short* rbf_bf = (unsigned short*)(((uintptr_t)(pDW + 36864) + 15) & ~(uintptr_t)15);
  unsigned short* after_rbf = rbf_bf + (size_t)NE * NRBF + 8;
  pv6* cmb = (pv6*)(((uintptr_t)after_rbf + 15) & ~(uintptr_t)15);           // NA*128 x 12B
  float* v_acc = (float*)(cmb + (size_t)NA * FDIM);                          // NA*3*128 f32

  hipMemsetAsync(deg, 0, NA * sizeof(int), stream);
  hipMemsetAsync(v_acc, 0, (size_t)NA * F3 * sizeof(float), stream);
  hipMemsetAsync(d_out, 0, NMOLS * sizeof(float), stream);

  prep_kernel<<<PACK_BLOCKS + NE / 256, 256, 0, stream>>>(
      msgW1, msgW2, updU, updV, updW1, updW2, rW1, distW, distb, pMsgW1,
      xyz, nbrs, unitv, rbf_bf, fcut, deg, slot_e, slot_j);
  msg0_mfma_kernel<<<NA / 16, 256, 0, stream>>>(emb, z, s, pMsgW1, msgb1, pMsgW2, msgb2, cmb);

  for (int l = 0; l < NLAYERS; l++) {
    edge_chunk_kernel<<<NA * MAXCH, 128, 0, stream>>>(
        cmb, v_acc, s, pDW + (size_t)l * 12288,
        deg, slot_e, slot_j, rbf_bf, fcut, unitv);
    int mode = (l == NLAYERS - 1) ? 1 : 0;
    int lnext = (l + 1 < NLAYERS) ? l + 1 : 0;
    upd_fused_kernel<<<NA / 16, 256, 0, stream>>>(
        s, v_acc, cmb, pUpdU + (size_t)l * 16384, pUpdV + (size_t)l * 16384,
        pUpdW1 + (size_t)l * 32768, updb1 + (size_t)l * FDIM,
        pUpdW2 + (size_t)l * 49152, updb2 + (size_t)l * F3,
        mode,
        pMsgW1 + (size_t)lnext * 16384, msgb1 + (size_t)lnext * FDIM,
        pMsgW2 + (size_t)lnext * 49152, msgb2 + (size_t)lnext * F3,
        pRW1, rb1, rW2, rb2, atom_e);
  }
  mol_reduce_kernel<<<(NA + 255) / 256, 256, 0, stream>>>(atom_e, mol, (float*)d_out);
}